// Round 13
// baseline (5084.426 us; speedup 1.0000x reference)
//
#include <hip/hip_runtime.h>
#include <hip/hip_bf16.h>

// RegisterEncoder: 8-layer pre-LN transformer, bf16 MFMA GEMMs, f32 residual.
// Round 13: revert R12 8-wave (fc2 140us). Keep R10-proven 4-wave pipeline;
// widen BN 128->256 for qkv/fc1 only (A-refetch 24x/32x -> 12x/16x, L3 traffic
// halved) -- same wave structure, same swizzle, NI=8, LDS 72KB, LPS=6.

typedef unsigned short u16;
typedef __attribute__((ext_vector_type(4))) float f32x4;
typedef __attribute__((ext_vector_type(8))) __bf16 bf16x8;

#define DEV static __device__ __forceinline__

constexpr int Bb = 16, Tt = 512, E = 1024, HD = 64, NHd = 16;
constexpr int DEPTH = 8, NREG = 16, LAT = 256, FF = 4096;
constexpr int S = Tt + NREG;   // 528
constexpr int SPAD = 576;      // padded attention seq (9 x 64)
constexpr int MR = Bb * S;     // 8448
constexpr int ME = Bb * Tt;    // 8192

DEV u16 f2bf(float f) {
  unsigned u = __builtin_bit_cast(unsigned, f);
  u += 0x7fffu + ((u >> 16) & 1u);
  return (u16)(u >> 16);
}
DEV float bf2f(u16 h) { return __builtin_bit_cast(float, (unsigned)h << 16); }

DEV void gll16(const u16* g, u16* l) {
  __builtin_amdgcn_global_load_lds((const __attribute__((address_space(1))) void*)g,
                                   (__attribute__((address_space(3))) void*)l, 16, 0, 0);
}

enum { M_EMBED, M_QKV, M_OPROJ, M_FC1, M_FC2, M_HEAD };

struct GA {
  const u16* A; const u16* Bt;
  int K, lda, ldb, Nrows, ldc;
  const float* bias; const float* pos;
  float* fout; u16* bout;
  u16 *qp, *kp, *vtp;
};

template<int MODE>
DEV void epilogue(const GA& g, int row, int col, float v) {
  if (MODE == M_EMBED) {
    const int b = row >> 9, t = row & 511;
    v += g.bias[col] + g.pos[(long)t * E + col];
    g.fout[((long)(b * S + t)) * E + col] = v;
  } else if (MODE == M_QKV) {
    const int b = row / S, s = row - b * S;
    v += g.bias[col];
    const int part = col >> 10, c = col & 1023;
    const int hh = c >> 6, d = c & 63;
    const u16 bf = f2bf(v);
    if (part == 0)      g.qp [((long)((b * NHd + hh) * SPAD + s)) * HD + d] = bf;
    else if (part == 1) g.kp [((long)((b * NHd + hh) * SPAD + s)) * HD + d] = bf;
    else                g.vtp[((long)((b * NHd + hh) * HD   + d)) * SPAD + s] = bf;
  } else if (MODE == M_OPROJ || MODE == M_FC2) {
    const long idx = (long)row * g.ldc + col;
    g.fout[idx] += v + g.bias[col];
  } else if (MODE == M_FC1) {
    v += g.bias[col];
    const float z = 0.7978845608028654f * (v + 0.044715f * v * v * v);
    const float e = __expf(2.f * z);
    const float th = 1.f - 2.f / (e + 1.f);   // tanh(z), overflow-safe
    g.bout[(long)row * g.ldc + col] = f2bf(0.5f * v * (1.f + th));
  } else if (MODE == M_HEAD) {
    g.fout[(long)row * g.ldc + col] = v + g.bias[col];
  }
}

// ---------------- 4-wave 128xBN GEMM (BN in {64,128,256}) ----------------
// R10-verified 3-buffer / counted-vmcnt / 1-barrier pipeline; both-sides
// XOR swizzle (conflicts=0 measured). BN=256 requires Nrows%256==0.
template<int MODE, int BN>
__global__ __launch_bounds__(256)
void gemm_bt(GA g) {
  constexpr int NI = BN / 32;                  // B fragments per wave
  constexpr int NSEG = (BN + 63) / 64;         // 64-row staging segments of B
  __shared__ __align__(16) u16 As[3][128 * 32];
  __shared__ __align__(16) u16 Bs[3][BN * 32];
  const int tid = threadIdx.x;
  const u16* A  = g.A;
  const u16* Bt = g.Bt;

  // bijective XCD swizzle (m204)
  int tM, tN;
  {
    const int nwg = gridDim.x * gridDim.y;
    int flat = blockIdx.y * gridDim.x + blockIdx.x;
    const int q = nwg >> 3, r = nwg & 7;
    const int xcd = flat & 7, loc = flat >> 3;
    flat = (xcd < r ? xcd * (q + 1) : r * (q + 1) + (xcd - r) * q) + loc;
    tM = flat / gridDim.x; tN = flat % gridDim.x;
  }

  const int lane = tid & 63, wid = tid >> 6;
  const int wr = wid >> 1, wc = wid & 1;
  const int fr = lane & 15, fg = lane >> 4;

  const int arow = tM * 128 + (tid >> 2);
  const int kseg = ((tid & 3) ^ ((tid >> 3) & 3)) * 8;   // pre-swizzled source chunk
  const int woff = (tid & 192) * 8;                      // wave-uniform LDS offset

  const u16* ag0 = A + (long)arow        * g.lda + kseg;
  const u16* ag1 = A + (long)(arow + 64) * g.lda + kseg;
  const u16* bgs[NSEG];
#pragma unroll
  for (int s = 0; s < NSEG; ++s) {
    int br = tN * BN + s * 64 + (tid >> 2);
    if (br > g.Nrows - 1) br = g.Nrows - 1;              // only possible for BN=64/128 tails
    bgs[s] = Bt + (long)br * g.ldb + kseg;
  }

  f32x4 acc[4][NI];
#pragma unroll
  for (int i = 0; i < 4; ++i)
#pragma unroll
    for (int j = 0; j < NI; ++j) acc[i][j] = f32x4{0.f, 0.f, 0.f, 0.f};

#define STAGE(KT, BUF) do {                                   \
    const int _k0 = (KT) << 5;                                \
    gll16(ag0 + _k0, &As[BUF][woff]);                         \
    gll16(ag1 + _k0, &As[BUF][woff + 2048]);                  \
    _Pragma("unroll")                                         \
    for (int s = 0; s < NSEG; ++s)                            \
      gll16(bgs[s] + _k0, &Bs[BUF][s * 2048 + woff]);         \
  } while (0)

  const int nk = g.K >> 5;
  STAGE(0, 0);
  if (nk > 1) STAGE(1, 1);

  const int rsw = (fg ^ ((fr >> 1) & 3)) * 8;          // read-side swizzle
  constexpr int LPS = 2 + NSEG;                        // gll16 per stage per lane

  for (int kt = 0; kt < nk; ++kt) {
    const int cur = kt % 3;
    if (kt < nk - 1) {
      asm volatile("s_waitcnt vmcnt(%0)" :: "i"(LPS) : "memory");
    } else {
      asm volatile("s_waitcnt vmcnt(0)" ::: "memory");
    }
    __builtin_amdgcn_sched_barrier(0);
    __builtin_amdgcn_s_barrier();
    __builtin_amdgcn_sched_barrier(0);
    if (kt + 2 < nk) STAGE(kt + 2, (kt + 2) % 3);

    bf16x8 af[4], bfr[NI];
#pragma unroll
    for (int mi = 0; mi < 4; ++mi)
      af[mi] = *(const bf16x8*)&As[cur][(wr * 64 + mi * 16 + fr) * 32 + rsw];
#pragma unroll
    for (int ni = 0; ni < NI; ++ni)
      bfr[ni] = *(const bf16x8*)&Bs[cur][(wc * (BN / 2) + ni * 16 + fr) * 32 + rsw];
    __builtin_amdgcn_s_setprio(1);
#pragma unroll
    for (int mi = 0; mi < 4; ++mi)
#pragma unroll
      for (int ni = 0; ni < NI; ++ni)
        acc[mi][ni] = __builtin_amdgcn_mfma_f32_16x16x32_bf16(af[mi], bfr[ni], acc[mi][ni], 0, 0, 0);
    __builtin_amdgcn_s_setprio(0);
  }
#undef STAGE

#pragma unroll
  for (int mi = 0; mi < 4; ++mi)
#pragma unroll
    for (int ni = 0; ni < NI; ++ni)
#pragma unroll
      for (int j = 0; j < 4; ++j)
        epilogue<MODE>(g, tM * 128 + wr * 64 + mi * 16 + fg * 4 + j,
                       tN * BN + wc * (BN / 2) + ni * 16 + fr, acc[mi][ni][j]);
}

// ---------------- fused flash attention, QBLK=128 (R10, kept) ----------------
__global__ __launch_bounds__(256)
void flash_k(const u16* __restrict__ q, const u16* __restrict__ k,
             const u16* __restrict__ vt, u16* __restrict__ o) {
  __shared__ __align__(16) u16 Ks[2][64 * 64];
  __shared__ __align__(16) u16 Vs[2][64 * 64];
  __shared__ __align__(16) u16 Ps[4 * 32 * 64];
  const int tid = threadIdx.x;
  const int lane = tid & 63, w = tid >> 6;
  const int fr = lane & 15, fg = lane >> 4;

  int flat = blockIdx.y * 5 + blockIdx.x;
  flat = (flat & 7) * 160 + (flat >> 3);
  const int bh = flat / 5, qt = flat % 5;
  const int q0 = qt * 128;

  bf16x8 qf[2][2];
#pragma unroll
  for (int ms = 0; ms < 2; ++ms) {
    int qr = q0 + w * 32 + ms * 16 + fr;
    if (qr > SPAD - 1) qr = SPAD - 1;
    const u16* qrow = q + ((long)bh * SPAD + qr) * HD;
    qf[ms][0] = *(const bf16x8*)(qrow + fg * 8);
    qf[ms][1] = *(const bf16x8*)(qrow + 32 + fg * 8);
  }

  const int srow = lane >> 3;
  const int sseg = (((lane & 7) ^ (srow & 7)) * 8);
  const u16* kg = k  + ((long)bh * SPAD + w * 16 + srow) * HD + sseg;
  const u16* vg = vt + ((long)(bh * HD + w * 16 + srow)) * SPAD + sseg;

#define STAGE_F(KT, BUF) do {                                       \
    gll16(kg + (KT) * 64 * HD,          &Ks[BUF][w * 16 * HD]);     \
    gll16(kg + (KT) * 64 * HD + 8 * HD, &Ks[BUF][w * 16 * HD + 8 * HD]); \
    gll16(vg + (KT) * 64,               &Vs[BUF][w * 16 * HD]);     \
    gll16(vg + (KT) * 64 + 8 * SPAD,    &Vs[BUF][w * 16 * HD + 8 * HD]); \
  } while (0)

  const int frm = fr & 7;

  float m[2][4], lsum[2][4]; f32x4 oa[2][4];
#pragma unroll
  for (int ms = 0; ms < 2; ++ms)
#pragma unroll
    for (int j = 0; j < 4; ++j) { m[ms][j] = -1e30f; lsum[ms][j] = 0.f; }
#pragma unroll
  for (int ms = 0; ms < 2; ++ms)
#pragma unroll
    for (int n = 0; n < 4; ++n) oa[ms][n] = f32x4{0.f, 0.f, 0.f, 0.f};

  const int nt = (qt < 4) ? 8 : 9;
  STAGE_F(0, 0);
  for (int kt = 0; kt < nt; ++kt) {
    const int cur = kt & 1;
    asm volatile("s_waitcnt vmcnt(0)" ::: "memory");
    __builtin_amdgcn_sched_barrier(0);
    __builtin_amdgcn_s_barrier();
    __builtin_amdgcn_sched_barrier(0);
    if (kt + 1 < nt) STAGE_F(kt + 1, cur ^ 1);

    f32x4 sfr[2][4];
#pragma unroll
    for (int n = 0; n < 4; ++n) {
      const bf16x8 kf0 = *(const bf16x8*)&Ks[cur][(n * 16 + fr) * HD + ((fg ^ frm) * 8)];
      const bf16x8 kf1 = *(const bf16x8*)&Ks[cur][(n * 16 + fr) * HD + (((fg + 4) ^ frm) * 8)];
#pragma unroll
      for (int ms = 0; ms < 2; ++ms) {
        sfr[ms][n] = __builtin_amdgcn_mfma_f32_16x16x32_bf16(qf[ms][0], kf0, f32x4{0.f,0.f,0.f,0.f}, 0, 0, 0);
        sfr[ms][n] = __builtin_amdgcn_mfma_f32_16x16x32_bf16(qf[ms][1], kf1, sfr[ms][n], 0, 0, 0);
      }
    }
    float p[2][4][4];
#pragma unroll
    for (int ms = 0; ms < 2; ++ms)
#pragma unroll
      for (int j = 0; j < 4; ++j) {
        const int qg = q0 + w * 32 + ms * 16 + fg * 4 + j;
        const int vlim = qg < Tt ? Tt : qg + 1;
#pragma unroll
        for (int n = 0; n < 4; ++n) {
          const int col = kt * 64 + n * 16 + fr;
          p[ms][n][j] = (col < vlim) ? sfr[ms][n][j] * 0.125f : -1e30f;
        }
      }
#pragma unroll
    for (int ms = 0; ms < 2; ++ms)
#pragma unroll
      for (int j = 0; j < 4; ++j) {
        float pm = fmaxf(fmaxf(p[ms][0][j], p[ms][1][j]), fmaxf(p[ms][2][j], p[ms][3][j]));
#pragma unroll
        for (int msk = 1; msk <= 8; msk <<= 1) pm = fmaxf(pm, __shfl_xor(pm, msk));
        const float mn = fmaxf(m[ms][j], pm);
        const float corr = __expf(m[ms][j] - mn);
        m[ms][j] = mn;
        float rs = 0.f;
#pragma unroll
        for (int n = 0; n < 4; ++n) { const float e = __expf(p[ms][n][j] - mn); p[ms][n][j] = e; rs += e; }
#pragma unroll
        for (int msk = 1; msk <= 8; msk <<= 1) rs += __shfl_xor(rs, msk);
        lsum[ms][j] = lsum[ms][j] * corr + rs;
#pragma unroll
        for (int n = 0; n < 4; ++n) oa[ms][n][j] *= corr;
      }
#pragma unroll
    for (int ms = 0; ms < 2; ++ms)
#pragma unroll
      for (int j = 0; j < 4; ++j) {
        const int r = ms * 16 + fg * 4 + j;
#pragma unroll
        for (int n = 0; n < 4; ++n) {
          const int gr = 2 * n + (fr >> 3);
          Ps[w * 2048 + r * 64 + ((gr ^ (r & 7)) * 8) + frm] = f2bf(p[ms][n][j]);
        }
      }
    asm volatile("s_waitcnt lgkmcnt(0)" ::: "memory");
    __builtin_amdgcn_sched_barrier(0);
    bf16x8 pf[2][2];
#pragma unroll
    for (int ms = 0; ms < 2; ++ms) {
      pf[ms][0] = *(const bf16x8*)&Ps[w * 2048 + (ms * 16 + fr) * 64 + ((fg ^ frm) * 8)];
      pf[ms][1] = *(const bf16x8*)&Ps[w * 2048 + (ms * 16 + fr) * 64 + (((fg + 4) ^ frm) * 8)];
    }
#pragma unroll
    for (int n = 0; n < 4; ++n) {
      const bf16x8 vf0 = *(const bf16x8*)&Vs[cur][(n * 16 + fr) * HD + ((fg ^ frm) * 8)];
      const bf16x8 vf1 = *(const bf16x8*)&Vs[cur][(n * 16 + fr) * HD + (((fg + 4) ^ frm) * 8)];
#pragma unroll
      for (int ms = 0; ms < 2; ++ms) {
        oa[ms][n] = __builtin_amdgcn_mfma_f32_16x16x32_bf16(pf[ms][0], vf0, oa[ms][n], 0, 0, 0);
        oa[ms][n] = __builtin_amdgcn_mfma_f32_16x16x32_bf16(pf[ms][1], vf1, oa[ms][n], 0, 0, 0);
      }
    }
  }
#undef STAGE_F

  const int b = bh >> 4, hh = bh & 15;
#pragma unroll
  for (int ms = 0; ms < 2; ++ms)
#pragma unroll
    for (int j = 0; j < 4; ++j) {
      const int qg = q0 + w * 32 + ms * 16 + fg * 4 + j;
      if (qg < S) {
        const float inv = 1.f / lsum[ms][j];
#pragma unroll
        for (int n = 0; n < 4; ++n)
          o[((long)(b * S + qg)) * E + hh * HD + n * 16 + fr] = f2bf(oa[ms][n][j] * inv);
      }
    }
}

// ---------------- LayerNorm ----------------
__global__ __launch_bounds__(256)
void ln_k(const float* __restrict__ x, const float* __restrict__ sc,
          const float* __restrict__ bi, u16* __restrict__ out, int gather) {
  const int r = blockIdx.x;
  const int srow = gather ? ((r >> 4) * S + Tt + (r & 15)) : r;
  const float4 v = ((const float4*)(x + (long)srow * E))[threadIdx.x];
  float s = v.x + v.y + v.z + v.w;
  float q = v.x * v.x + v.y * v.y + v.z * v.z + v.w * v.w;
#pragma unroll
  for (int o = 32; o; o >>= 1) { s += __shfl_down(s, o); q += __shfl_down(q, o); }
  __shared__ float ps[8];
  if ((threadIdx.x & 63) == 0) { ps[threadIdx.x >> 6] = s; ps[4 + (threadIdx.x >> 6)] = q; }
  __syncthreads();
  s = ps[0] + ps[1] + ps[2] + ps[3];
  q = ps[4] + ps[5] + ps[6] + ps[7];
  const float mean = s * (1.f / E);
  const float rs = rsqrtf(q * (1.f / E) - mean * mean + 1e-5f);
  const int c = threadIdx.x * 4;
  ushort4 o4;
  o4.x = f2bf((v.x - mean) * rs * sc[c + 0] + bi[c + 0]);
  o4.y = f2bf((v.y - mean) * rs * sc[c + 1] + bi[c + 1]);
  o4.z = f2bf((v.z - mean) * rs * sc[c + 2] + bi[c + 2]);
  o4.w = f2bf((v.w - mean) * rs * sc[c + 3] + bi[c + 3]);
  ((ushort4*)(out + (long)r * E))[threadIdx.x] = o4;
}

// ---------------- transpose f32[R,C] -> bf16[C,R] ----------------
__global__ __launch_bounds__(256)
void wtrans(const float* __restrict__ src, u16* __restrict__ dst, int R, int C) {
  __shared__ float t[32][33];
  const int c0 = blockIdx.x * 32, r0 = blockIdx.y * 32;
  const int tx = threadIdx.x & 31, ty = threadIdx.x >> 5;
#pragma unroll
  for (int i = 0; i < 32; i += 8) t[ty + i][tx] = src[(long)(r0 + ty + i) * C + c0 + tx];
  __syncthreads();
#pragma unroll
  for (int i = 0; i < 32; i += 8) dst[(long)(c0 + ty + i) * R + r0 + tx] = f2bf(t[tx][ty + i]);
}

// ---------------- merged per-layer weight transpose (4 weights, 1 launch) ----
struct WT4 {
  const float* s[4]; u16* d[4];
  int R[4], C[4], tx[4], st[4];
};
__global__ __launch_bounds__(256)
void wtrans4(WT4 a) {
  const int bid = blockIdx.x;
  const int wsel = (bid >= a.st[1]) + (bid >= a.st[2]) + (bid >= a.st[3]);
  const int t = bid - a.st[wsel];
  const int c0 = (t % a.tx[wsel]) * 32, r0 = (t / a.tx[wsel]) * 32;
  const float* src = a.s[wsel]; u16* dst = a.d[wsel];
  const int R = a.R[wsel], C = a.C[wsel];
  __shared__ float tt[32][33];
  const int tx = threadIdx.x & 31, ty = threadIdx.x >> 5;
#pragma unroll
  for (int i = 0; i < 32; i += 8) tt[ty + i][tx] = src[(long)(r0 + ty + i) * C + c0 + tx];
  __syncthreads();
#pragma unroll
  for (int i = 0; i < 32; i += 8) dst[(long)(c0 + ty + i) * R + r0 + tx] = f2bf(tt[tx][ty + i]);
}

// ---------------- small utility kernels ----------------
__global__ void cvt_bf(const float* __restrict__ in, u16* __restrict__ out, long n) {
  const long i = ((long)blockIdx.x * blockDim.x + threadIdx.x) * 4;
  if (i >= n) return;
  const float4 v = *(const float4*)(in + i);
  ushort4 o; o.x = f2bf(v.x); o.y = f2bf(v.y); o.z = f2bf(v.z); o.w = f2bf(v.w);
  *(ushort4*)(out + i) = o;
}

__global__ void zero_k(float4* p, long n) {
  long i = (long)blockIdx.x * blockDim.x + threadIdx.x;
  const long st = (long)gridDim.x * blockDim.x;
  const float4 z = make_float4(0.f, 0.f, 0.f, 0.f);
  for (; i < n; i += st) p[i] = z;
}

__global__ void reg_copy(const float* __restrict__ regs, float* __restrict__ x) {
  const int b = blockIdx.x >> 4, r = blockIdx.x & 15;
  const float4* sp = (const float4*)(regs + (long)r * E);
  float4* dp = (float4*)(x + ((long)(b * S + Tt + r)) * E);
  dp[threadIdx.x] = sp[threadIdx.x];
}

// ---------------- workspace layout (bytes, all 16-aligned) ----------------
constexpr long OFF_WQKV = 0L;                                // per-layer, reused
constexpr long OFF_WO   = OFF_WQKV + 3072L * 1024 * 2;
constexpr long OFF_WFC1 = OFF_WO   + 1024L * 1024 * 2;
constexpr long OFF_WFC2 = OFF_WFC1 + 4096L * 1024 * 2;
constexpr long OFF_WEMB = OFF_WFC2 + 1024L * 4096 * 2;
constexpr long OFF_WHEAD= OFF_WEMB + 1024L * 64 * 2;
constexpr long OFF_SMP  = OFF_WHEAD+ 256L * 1024 * 2;
constexpr long OFF_X    = OFF_SMP  + (long)ME * 64 * 2;
constexpr long OFF_H    = OFF_X    + (long)MR * E * 4;
constexpr long OFF_Q    = OFF_H    + (long)MR * E * 2;
constexpr long OFF_K    = OFF_Q    + 256L * SPAD * HD * 2;
constexpr long OFF_VT   = OFF_K    + 256L * SPAD * HD * 2;
constexpr long OFF_O    = OFF_VT   + 256L * SPAD * HD * 2;   // a1 overlays o
constexpr long OFF_HF   = OFF_O    + (long)MR * FF * 2;
constexpr long WS_NEED  = OFF_HF   + 256L * 1024 * 2;        // ~196 MB

extern "C" void kernel_launch(void* const* d_in, const int* in_sizes, int n_in,
                              void* d_out, int out_size, void* d_ws, size_t ws_size,
                              hipStream_t stream) {
  if (ws_size < (size_t)WS_NEED) return;

  const float* sample = (const float*)d_in[0];
  const float* W_emb  = (const float*)d_in[1];
  const float* b_emb  = (const float*)d_in[2];
  const float* pos    = (const float*)d_in[3];
  const float* regs   = (const float*)d_in[4];
  const float* ln1_s  = (const float*)d_in[5];
  const float* ln1_b  = (const float*)d_in[6];
  const float* W_qkv  = (const float*)d_in[7];
  const float* b_qkv  = (const float*)d_in[8];
  const float* W_o    = (const float*)d_in[9];
  const float* b_o    = (const float*)d_in[10];
  const float* ln2_s  = (const float*)d_in[11];
  const float* ln2_b  = (const float*)d_in[12];
  const float* W_fc1  = (const float*)d_in[13];
  const float* b_fc1  = (const float*)d_in[14];
  const float* W_fc2  = (const float*)d_in[15];
  const float* b_fc2  = (const float*)d_in[16];
  const float* lnf_s  = (const float*)d_in[17];
  const float* lnf_b  = (const float*)d_in[18];
  const float* W_head = (const float*)d_in[19];
  const float* b_head = (const float*)d_in[20];

  char* w = (char*)d_ws;
  u16* wqkvT = (u16*)(w + OFF_WQKV);
  u16* woT   = (u16*)(w + OFF_WO);
  u16* wfc1T = (u16*)(w + OFF_WFC1);
  u16* wfc2T = (u16*)(w + OFF_WFC2);
  u16* wembT = (u16*)(w + OFF_WEMB);
  u16* wheadT= (u16*)(w + OFF_WHEAD);
  u16* smp   = (u16*)(w + OFF_SMP);
  float* x   = (float*)(w + OFF_X);
  u16* h     = (u16*)(w + OFF_H);
  u16* qp    = (u16*)(w + OFF_Q);
  u16* kp    = (u16*)(w + OFF_K);
  u16* vtp   = (u16*)(w + OFF_VT);
  u16* o     = (u16*)(w + OFF_O);
  u16* a1    = (u16*)(w + OFF_O);   // overlay: o dead when a1 live
  u16* hf    = (u16*)(w + OFF_HF);

  // ---- one-time prep ----
  wtrans<<<dim3(32, 2, 1), 256, 0, stream>>>(W_emb,  wembT, 64, 1024);
  wtrans<<<dim3(8, 32, 1), 256, 0, stream>>>(W_head, wheadT, 1024, 256);
  cvt_bf<<<dim3(512), 256, 0, stream>>>(sample, smp, (long)ME * 64);
  zero_k<<<dim3(2048), 256, 0, stream>>>((float4*)qp, (3L * 256 * SPAD * HD * 2) / 16);

  // ---- embed + registers ----
  {
    GA g{}; g.A = smp; g.Bt = wembT; g.K = 64; g.lda = 64; g.ldb = 64;
    g.Nrows = E; g.bias = b_emb; g.pos = pos; g.fout = x;
    gemm_bt<M_EMBED, 64><<<dim3(16, 64, 1), 256, 0, stream>>>(g);
  }
  reg_copy<<<dim3(256), 256, 0, stream>>>(regs, x);

  for (int L = 0; L < DEPTH; ++L) {
    {
      WT4 a;
      a.s[0] = W_qkv + (long)L * 1024 * 3072; a.d[0] = wqkvT; a.R[0] = 1024; a.C[0] = 3072; a.tx[0] = 96;  a.st[0] = 0;
      a.s[1] = W_o   + (long)L * 1024 * 1024; a.d[1] = woT;   a.R[1] = 1024; a.C[1] = 1024; a.tx[1] = 32;  a.st[1] = 3072;
      a.s[2] = W_fc1 + (long)L * 1024 * 4096; a.d[2] = wfc1T; a.R[2] = 1024; a.C[2] = 4096; a.tx[2] = 128; a.st[2] = 4096;
      a.s[3] = W_fc2 + (long)L * 4096 * 1024; a.d[3] = wfc2T; a.R[3] = 4096; a.C[3] = 1024; a.tx[3] = 32;  a.st[3] = 8192;
      wtrans4<<<dim3(12288), 256, 0, stream>>>(a);
    }

    ln_k<<<dim3(MR), 256, 0, stream>>>(x, ln1_s + L * E, ln1_b + L * E, h, 0);
    {
      GA g{}; g.A = h; g.Bt = wqkvT;
      g.K = 1024; g.lda = 1024; g.ldb = 1024; g.Nrows = 3072;
      g.bias = b_qkv + L * 3072; g.qp = qp; g.kp = kp; g.vtp = vtp;
      gemm_bt<M_QKV, 256><<<dim3(12, 66, 1), 256, 0, stream>>>(g);
    }
    flash_k<<<dim3(5, 256, 1), 256, 0, stream>>>(qp, kp, vtp, o);
    {
      GA g{}; g.A = o; g.Bt = woT;
      g.K = 1024; g.lda = 1024; g.ldb = 1024; g.Nrows = 1024; g.ldc = 1024;
      g.bias = b_o + L * E; g.fout = x;
      gemm_bt<M_OPROJ, 128><<<dim3(8, 66, 1), 256, 0, stream>>>(g);
    }
    ln_k<<<dim3(MR), 256, 0, stream>>>(x, ln2_s + L * E, ln2_b + L * E, h, 0);
    {
      GA g{}; g.A = h; g.Bt = wfc1T;
      g.K = 1024; g.lda = 1024; g.ldb = 1024; g.Nrows = 4096; g.ldc = 4096;
      g.bias = b_fc1 + L * FF; g.bout = a1;
      gemm_bt<M_FC1, 256><<<dim3(16, 66, 1), 256, 0, stream>>>(g);
    }
    {
      GA g{}; g.A = a1; g.Bt = wfc2T;
      g.K = 4096; g.lda = 4096; g.ldb = 4096; g.Nrows = 1024; g.ldc = 1024;
      g.bias = b_fc2 + L * E; g.fout = x;
      gemm_bt<M_FC2, 128><<<dim3(8, 66, 1), 256, 0, stream>>>(g);
    }
  }

  ln_k<<<dim3(256), 256, 0, stream>>>(x, lnf_s, lnf_b, hf, 1);
  {
    GA g{}; g.A = hf; g.Bt = wheadT; g.K = 1024; g.lda = 1024; g.ldb = 1024;
    g.Nrows = LAT; g.ldc = LAT; g.bias = b_head; g.fout = (float*)d_out;
    gemm_bt<M_HEAD, 128><<<dim3(2, 2, 1), 256, 0, stream>>>(g);
  }
}

// Round 14
// 4212.984 us; speedup vs baseline: 1.2068x; 1.2068x over previous
//
#include <hip/hip_runtime.h>
#include <hip/hip_bf16.h>

// RegisterEncoder: 8-layer pre-LN transformer, bf16 MFMA GEMMs, f32 residual.
// Round 14: full revert to R10 (3886us proven) + ONE zero-risk change: the
// GEMM block-index map adds 2x2 supertiling after the XCD chunk remap, so 4
// consecutive blocks on an XCD share 2 A-tiles + 2 B-tiles (4MB, L2-fits)
// instead of streaming B from L3 (tests the L3-BW theory with an index-only
// probe; inner loop untouched).

typedef unsigned short u16;
typedef __attribute__((ext_vector_type(4))) float f32x4;
typedef __attribute__((ext_vector_type(8))) __bf16 bf16x8;

#define DEV static __device__ __forceinline__

constexpr int Bb = 16, Tt = 512, E = 1024, HD = 64, NHd = 16;
constexpr int DEPTH = 8, NREG = 16, LAT = 256, FF = 4096;
constexpr int S = Tt + NREG;   // 528
constexpr int SPAD = 576;      // padded attention seq (9 x 64)
constexpr int MR = Bb * S;     // 8448
constexpr int ME = Bb * Tt;    // 8192

DEV u16 f2bf(float f) {
  unsigned u = __builtin_bit_cast(unsigned, f);
  u += 0x7fffu + ((u >> 16) & 1u);
  return (u16)(u >> 16);
}
DEV float bf2f(u16 h) { return __builtin_bit_cast(float, (unsigned)h << 16); }

DEV void gll16(const u16* g, u16* l) {
  __builtin_amdgcn_global_load_lds((const __attribute__((address_space(1))) void*)g,
                                   (__attribute__((address_space(3))) void*)l, 16, 0, 0);
}

// ---------------- GEMM: C[M,N] = A[M,K](bf16) * Bt[N,K]^T(bf16) ----------------
enum { M_EMBED, M_QKV, M_OPROJ, M_FC1, M_FC2, M_HEAD };

struct GA {
  const u16* A; const u16* Bt;
  int K, lda, ldb, Nrows, ldc;
  const float* bias; const float* pos;
  float* fout; u16* bout;
  u16 *qp, *kp, *vtp;
};

template<int MODE, int BN>
__global__ __launch_bounds__(256)
void gemm_bt(GA g) {
  constexpr int NI = BN / 32;                  // B fragments per wave
  __shared__ __align__(16) u16 As[3][128 * 32];
  __shared__ __align__(16) u16 Bs[3][BN * 32];
  const int tid = threadIdx.x;
  const u16* A  = g.A;
  const u16* Bt = g.Bt;

  // bijective XCD swizzle (m204) + 2x2 supertile for per-XCD L2 reuse.
  // All call sites have even M-tile and N-tile counts (bijective).
  int tM, tN;
  {
    const int nwg = gridDim.x * gridDim.y;
    int flat = blockIdx.y * gridDim.x + blockIdx.x;
    const int q = nwg >> 3, r = nwg & 7;
    const int xcd = flat & 7, loc = flat >> 3;
    flat = (xcd < r ? xcd * (q + 1) : r * (q + 1) + (xcd - r) * q) + loc;
    const int quad = flat >> 2, dm = (flat >> 1) & 1, dn = flat & 1;
    const int halfM = gridDim.y >> 1;
    const int qm = quad % halfM, qn = quad / halfM;
    tM = 2 * qm + dm; tN = 2 * qn + dn;
  }

  const int lane = tid & 63, wid = tid >> 6;
  const int wr = wid >> 1, wc = wid & 1;       // 2x2 waves
  const int fr = lane & 15, fg = lane >> 4;

  const int arow = tM * 128 + (tid >> 2);
  int br0 = tN * BN + (tid >> 2);
  if (br0 > g.Nrows - 1) br0 = g.Nrows - 1;
  int br1 = tN * BN + 64 + (tid >> 2);
  if (br1 > g.Nrows - 1) br1 = g.Nrows - 1;
  // pre-swizzled SOURCE chunk (both-sides swizzle, rule #21)
  const int kseg = ((tid & 3) ^ ((tid >> 3) & 3)) * 8;
  const int woff = (tid & 192) * 8;            // wave-uniform LDS offset (elems)

  const u16* ag0 = A  + (long)arow        * g.lda + kseg;
  const u16* ag1 = A  + (long)(arow + 64) * g.lda + kseg;
  const u16* bg0 = Bt + (long)br0         * g.ldb + kseg;
  const u16* bg1 = Bt + (long)br1         * g.ldb + kseg;

  f32x4 acc[4][NI];
#pragma unroll
  for (int i = 0; i < 4; ++i)
#pragma unroll
    for (int j = 0; j < NI; ++j) acc[i][j] = f32x4{0.f, 0.f, 0.f, 0.f};

#define STAGE(KT, BUF) do {                                   \
    const int _k0 = (KT) << 5;                                \
    gll16(ag0 + _k0, &As[BUF][woff]);                         \
    gll16(ag1 + _k0, &As[BUF][woff + 2048]);                  \
    gll16(bg0 + _k0, &Bs[BUF][woff]);                         \
    if (BN == 128) gll16(bg1 + _k0, &Bs[BUF][woff + 2048]);   \
  } while (0)

  const int nk = g.K >> 5;
  STAGE(0, 0);
  if (nk > 1) STAGE(1, 1);

  // read-side swizzle: physical chunk for logical fg of row (..+fr)
  const int rsw = (fg ^ ((fr >> 1) & 3)) * 8;
  constexpr int LPS = (BN == 128) ? 4 : 3;     // loads per stage

  for (int kt = 0; kt < nk; ++kt) {
    const int cur = kt % 3;
    if (kt < nk - 1) {
      asm volatile("s_waitcnt vmcnt(%0)" :: "i"(LPS) : "memory");
    } else {
      asm volatile("s_waitcnt vmcnt(0)" ::: "memory");
    }
    __builtin_amdgcn_sched_barrier(0);
    __builtin_amdgcn_s_barrier();
    __builtin_amdgcn_sched_barrier(0);
    if (kt + 2 < nk) STAGE(kt + 2, (kt + 2) % 3);

    bf16x8 af[4], bfr[NI];
#pragma unroll
    for (int mi = 0; mi < 4; ++mi)
      af[mi] = *(const bf16x8*)&As[cur][(wr * 64 + mi * 16 + fr) * 32 + rsw];
#pragma unroll
    for (int ni = 0; ni < NI; ++ni)
      bfr[ni] = *(const bf16x8*)&Bs[cur][(wc * (BN / 2) + ni * 16 + fr) * 32 + rsw];
    __builtin_amdgcn_s_setprio(1);
#pragma unroll
    for (int mi = 0; mi < 4; ++mi)
#pragma unroll
      for (int ni = 0; ni < NI; ++ni)
        acc[mi][ni] = __builtin_amdgcn_mfma_f32_16x16x32_bf16(af[mi], bfr[ni], acc[mi][ni], 0, 0, 0);
    __builtin_amdgcn_s_setprio(0);
  }
#undef STAGE

#pragma unroll
  for (int mi = 0; mi < 4; ++mi)
#pragma unroll
    for (int ni = 0; ni < NI; ++ni)
#pragma unroll
      for (int j = 0; j < 4; ++j) {
        const int row = tM * 128 + wr * 64 + mi * 16 + fg * 4 + j;
        const int col = tN * BN + wc * (BN / 2) + ni * 16 + fr;
        float v = acc[mi][ni][j];
        if (MODE == M_EMBED) {
          const int b = row >> 9, t = row & 511;
          v += g.bias[col] + g.pos[(long)t * E + col];
          g.fout[((long)(b * S + t)) * E + col] = v;
        } else if (MODE == M_QKV) {
          const int b = row / S, s = row - b * S;
          v += g.bias[col];
          const int part = col >> 10, c = col & 1023;
          const int hh = c >> 6, d = c & 63;
          const u16 bf = f2bf(v);
          if (part == 0)      g.qp [((long)((b * NHd + hh) * SPAD + s)) * HD + d] = bf;
          else if (part == 1) g.kp [((long)((b * NHd + hh) * SPAD + s)) * HD + d] = bf;
          else                g.vtp[((long)((b * NHd + hh) * HD   + d)) * SPAD + s] = bf;
        } else if (MODE == M_OPROJ || MODE == M_FC2) {
          const long idx = (long)row * g.ldc + col;
          g.fout[idx] += v + g.bias[col];
        } else if (MODE == M_FC1) {
          v += g.bias[col];
          const float z = 0.7978845608028654f * (v + 0.044715f * v * v * v);
          const float e = __expf(2.f * z);
          const float th = 1.f - 2.f / (e + 1.f);   // tanh(z), overflow-safe
          g.bout[(long)row * g.ldc + col] = f2bf(0.5f * v * (1.f + th));
        } else if (MODE == M_HEAD) {
          g.fout[(long)row * g.ldc + col] = v + g.bias[col];
        }
      }
}

// ---------------- fused flash attention, QBLK=128 (R10, kept) ----------------
__global__ __launch_bounds__(256)
void flash_k(const u16* __restrict__ q, const u16* __restrict__ k,
             const u16* __restrict__ vt, u16* __restrict__ o) {
  __shared__ __align__(16) u16 Ks[2][64 * 64];
  __shared__ __align__(16) u16 Vs[2][64 * 64];   // VT tile: [d][kv]
  __shared__ __align__(16) u16 Ps[4 * 32 * 64];
  const int tid = threadIdx.x;
  const int lane = tid & 63, w = tid >> 6;
  const int fr = lane & 15, fg = lane >> 4;

  // XCD swizzle: 1280 blocks % 8 == 0; contiguous bh chunks per XCD
  int flat = blockIdx.y * 5 + blockIdx.x;
  flat = (flat & 7) * 160 + (flat >> 3);
  const int bh = flat / 5, qt = flat % 5;
  const int q0 = qt * 128;

  bf16x8 qf[2][2];
#pragma unroll
  for (int ms = 0; ms < 2; ++ms) {
    int qr = q0 + w * 32 + ms * 16 + fr;
    if (qr > SPAD - 1) qr = SPAD - 1;
    const u16* qrow = q + ((long)bh * SPAD + qr) * HD;
    qf[ms][0] = *(const bf16x8*)(qrow + fg * 8);
    qf[ms][1] = *(const bf16x8*)(qrow + 32 + fg * 8);
  }

  const int srow = lane >> 3;
  const int sseg = (((lane & 7) ^ (srow & 7)) * 8);
  const u16* kg = k  + ((long)bh * SPAD + w * 16 + srow) * HD + sseg;
  const u16* vg = vt + ((long)(bh * HD + w * 16 + srow)) * SPAD + sseg;

#define STAGE_F(KT, BUF) do {                                       \
    gll16(kg + (KT) * 64 * HD,          &Ks[BUF][w * 16 * HD]);     \
    gll16(kg + (KT) * 64 * HD + 8 * HD, &Ks[BUF][w * 16 * HD + 8 * HD]); \
    gll16(vg + (KT) * 64,               &Vs[BUF][w * 16 * HD]);     \
    gll16(vg + (KT) * 64 + 8 * SPAD,    &Vs[BUF][w * 16 * HD + 8 * HD]); \
  } while (0)

  const int frm = fr & 7;

  float m[2][4], lsum[2][4]; f32x4 oa[2][4];
#pragma unroll
  for (int ms = 0; ms < 2; ++ms)
#pragma unroll
    for (int j = 0; j < 4; ++j) { m[ms][j] = -1e30f; lsum[ms][j] = 0.f; }
#pragma unroll
  for (int ms = 0; ms < 2; ++ms)
#pragma unroll
    for (int n = 0; n < 4; ++n) oa[ms][n] = f32x4{0.f, 0.f, 0.f, 0.f};

  const int nt = (qt < 4) ? 8 : 9;
  STAGE_F(0, 0);
  for (int kt = 0; kt < nt; ++kt) {
    const int cur = kt & 1;
    asm volatile("s_waitcnt vmcnt(0)" ::: "memory");
    __builtin_amdgcn_sched_barrier(0);
    __builtin_amdgcn_s_barrier();
    __builtin_amdgcn_sched_barrier(0);
    if (kt + 1 < nt) STAGE_F(kt + 1, cur ^ 1);

    f32x4 sfr[2][4];
#pragma unroll
    for (int n = 0; n < 4; ++n) {
      const bf16x8 kf0 = *(const bf16x8*)&Ks[cur][(n * 16 + fr) * HD + ((fg ^ frm) * 8)];
      const bf16x8 kf1 = *(const bf16x8*)&Ks[cur][(n * 16 + fr) * HD + (((fg + 4) ^ frm) * 8)];
#pragma unroll
      for (int ms = 0; ms < 2; ++ms) {
        sfr[ms][n] = __builtin_amdgcn_mfma_f32_16x16x32_bf16(qf[ms][0], kf0, f32x4{0.f,0.f,0.f,0.f}, 0, 0, 0);
        sfr[ms][n] = __builtin_amdgcn_mfma_f32_16x16x32_bf16(qf[ms][1], kf1, sfr[ms][n], 0, 0, 0);
      }
    }
    float p[2][4][4];
#pragma unroll
    for (int ms = 0; ms < 2; ++ms)
#pragma unroll
      for (int j = 0; j < 4; ++j) {
        const int qg = q0 + w * 32 + ms * 16 + fg * 4 + j;
        const int vlim = qg < Tt ? Tt : qg + 1;
#pragma unroll
        for (int n = 0; n < 4; ++n) {
          const int col = kt * 64 + n * 16 + fr;
          p[ms][n][j] = (col < vlim) ? sfr[ms][n][j] * 0.125f : -1e30f;
        }
      }
#pragma unroll
    for (int ms = 0; ms < 2; ++ms)
#pragma unroll
      for (int j = 0; j < 4; ++j) {
        float pm = fmaxf(fmaxf(p[ms][0][j], p[ms][1][j]), fmaxf(p[ms][2][j], p[ms][3][j]));
#pragma unroll
        for (int msk = 1; msk <= 8; msk <<= 1) pm = fmaxf(pm, __shfl_xor(pm, msk));
        const float mn = fmaxf(m[ms][j], pm);
        const float corr = __expf(m[ms][j] - mn);
        m[ms][j] = mn;
        float rs = 0.f;
#pragma unroll
        for (int n = 0; n < 4; ++n) { const float e = __expf(p[ms][n][j] - mn); p[ms][n][j] = e; rs += e; }
#pragma unroll
        for (int msk = 1; msk <= 8; msk <<= 1) rs += __shfl_xor(rs, msk);
        lsum[ms][j] = lsum[ms][j] * corr + rs;
#pragma unroll
        for (int n = 0; n < 4; ++n) oa[ms][n][j] *= corr;
      }
#pragma unroll
    for (int ms = 0; ms < 2; ++ms)
#pragma unroll
      for (int j = 0; j < 4; ++j) {
        const int r = ms * 16 + fg * 4 + j;
#pragma unroll
        for (int n = 0; n < 4; ++n) {
          const int gr = 2 * n + (fr >> 3);
          Ps[w * 2048 + r * 64 + ((gr ^ (r & 7)) * 8) + frm] = f2bf(p[ms][n][j]);
        }
      }
    asm volatile("s_waitcnt lgkmcnt(0)" ::: "memory");
    __builtin_amdgcn_sched_barrier(0);
    bf16x8 pf[2][2];
#pragma unroll
    for (int ms = 0; ms < 2; ++ms) {
      pf[ms][0] = *(const bf16x8*)&Ps[w * 2048 + (ms * 16 + fr) * 64 + ((fg ^ frm) * 8)];
      pf[ms][1] = *(const bf16x8*)&Ps[w * 2048 + (ms * 16 + fr) * 64 + (((fg + 4) ^ frm) * 8)];
    }
#pragma unroll
    for (int n = 0; n < 4; ++n) {
      const bf16x8 vf0 = *(const bf16x8*)&Vs[cur][(n * 16 + fr) * HD + ((fg ^ frm) * 8)];
      const bf16x8 vf1 = *(const bf16x8*)&Vs[cur][(n * 16 + fr) * HD + (((fg + 4) ^ frm) * 8)];
#pragma unroll
      for (int ms = 0; ms < 2; ++ms) {
        oa[ms][n] = __builtin_amdgcn_mfma_f32_16x16x32_bf16(pf[ms][0], vf0, oa[ms][n], 0, 0, 0);
        oa[ms][n] = __builtin_amdgcn_mfma_f32_16x16x32_bf16(pf[ms][1], vf1, oa[ms][n], 0, 0, 0);
      }
    }
  }
#undef STAGE_F

  const int b = bh >> 4, hh = bh & 15;
#pragma unroll
  for (int ms = 0; ms < 2; ++ms)
#pragma unroll
    for (int j = 0; j < 4; ++j) {
      const int qg = q0 + w * 32 + ms * 16 + fg * 4 + j;
      if (qg < S) {
        const float inv = 1.f / lsum[ms][j];
#pragma unroll
        for (int n = 0; n < 4; ++n)
          o[((long)(b * S + qg)) * E + hh * HD + n * 16 + fr] = f2bf(oa[ms][n][j] * inv);
      }
    }
}

// ---------------- LayerNorm ----------------
__global__ __launch_bounds__(256)
void ln_k(const float* __restrict__ x, const float* __restrict__ sc,
          const float* __restrict__ bi, u16* __restrict__ out, int gather) {
  const int r = blockIdx.x;
  const int srow = gather ? ((r >> 4) * S + Tt + (r & 15)) : r;
  const float4 v = ((const float4*)(x + (long)srow * E))[threadIdx.x];
  float s = v.x + v.y + v.z + v.w;
  float q = v.x * v.x + v.y * v.y + v.z * v.z + v.w * v.w;
#pragma unroll
  for (int o = 32; o; o >>= 1) { s += __shfl_down(s, o); q += __shfl_down(q, o); }
  __shared__ float ps[8];
  if ((threadIdx.x & 63) == 0) { ps[threadIdx.x >> 6] = s; ps[4 + (threadIdx.x >> 6)] = q; }
  __syncthreads();
  s = ps[0] + ps[1] + ps[2] + ps[3];
  q = ps[4] + ps[5] + ps[6] + ps[7];
  const float mean = s * (1.f / E);
  const float rs = rsqrtf(q * (1.f / E) - mean * mean + 1e-5f);
  const int c = threadIdx.x * 4;
  ushort4 o4;
  o4.x = f2bf((v.x - mean) * rs * sc[c + 0] + bi[c + 0]);
  o4.y = f2bf((v.y - mean) * rs * sc[c + 1] + bi[c + 1]);
  o4.z = f2bf((v.z - mean) * rs * sc[c + 2] + bi[c + 2]);
  o4.w = f2bf((v.w - mean) * rs * sc[c + 3] + bi[c + 3]);
  ((ushort4*)(out + (long)r * E))[threadIdx.x] = o4;
}

// ---------------- transpose f32[R,C] -> bf16[C,R] ----------------
__global__ __launch_bounds__(256)
void wtrans(const float* __restrict__ src, u16* __restrict__ dst, int R, int C) {
  __shared__ float t[32][33];
  const int c0 = blockIdx.x * 32, r0 = blockIdx.y * 32;
  const int tx = threadIdx.x & 31, ty = threadIdx.x >> 5;
#pragma unroll
  for (int i = 0; i < 32; i += 8) t[ty + i][tx] = src[(long)(r0 + ty + i) * C + c0 + tx];
  __syncthreads();
#pragma unroll
  for (int i = 0; i < 32; i += 8) dst[(long)(c0 + ty + i) * R + r0 + tx] = f2bf(t[tx][ty + i]);
}

// ---------------- merged per-layer weight transpose (4 weights, 1 launch) ----
struct WT4 {
  const float* s[4]; u16* d[4];
  int R[4], C[4], tx[4], st[4];
};
__global__ __launch_bounds__(256)
void wtrans4(WT4 a) {
  const int bid = blockIdx.x;
  const int wsel = (bid >= a.st[1]) + (bid >= a.st[2]) + (bid >= a.st[3]);
  const int t = bid - a.st[wsel];
  const int c0 = (t % a.tx[wsel]) * 32, r0 = (t / a.tx[wsel]) * 32;
  const float* src = a.s[wsel]; u16* dst = a.d[wsel];
  const int R = a.R[wsel], C = a.C[wsel];
  __shared__ float tt[32][33];
  const int tx = threadIdx.x & 31, ty = threadIdx.x >> 5;
#pragma unroll
  for (int i = 0; i < 32; i += 8) tt[ty + i][tx] = src[(long)(r0 + ty + i) * C + c0 + tx];
  __syncthreads();
#pragma unroll
  for (int i = 0; i < 32; i += 8) dst[(long)(c0 + ty + i) * R + r0 + tx] = f2bf(tt[tx][ty + i]);
}

// ---------------- small utility kernels ----------------
__global__ void cvt_bf(const float* __restrict__ in, u16* __restrict__ out, long n) {
  const long i = ((long)blockIdx.x * blockDim.x + threadIdx.x) * 4;
  if (i >= n) return;
  const float4 v = *(const float4*)(in + i);
  ushort4 o; o.x = f2bf(v.x); o.y = f2bf(v.y); o.z = f2bf(v.z); o.w = f2bf(v.w);
  *(ushort4*)(out + i) = o;
}

__global__ void zero_k(float4* p, long n) {
  long i = (long)blockIdx.x * blockDim.x + threadIdx.x;
  const long st = (long)gridDim.x * blockDim.x;
  const float4 z = make_float4(0.f, 0.f, 0.f, 0.f);
  for (; i < n; i += st) p[i] = z;
}

__global__ void reg_copy(const float* __restrict__ regs, float* __restrict__ x) {
  const int b = blockIdx.x >> 4, r = blockIdx.x & 15;
  const float4* sp = (const float4*)(regs + (long)r * E);
  float4* dp = (float4*)(x + ((long)(b * S + Tt + r)) * E);
  dp[threadIdx.x] = sp[threadIdx.x];
}

// ---------------- workspace layout (bytes, all 16-aligned) ----------------
constexpr long OFF_WQKV = 0L;                                // per-layer, reused
constexpr long OFF_WO   = OFF_WQKV + 3072L * 1024 * 2;
constexpr long OFF_WFC1 = OFF_WO   + 1024L * 1024 * 2;
constexpr long OFF_WFC2 = OFF_WFC1 + 4096L * 1024 * 2;
constexpr long OFF_WEMB = OFF_WFC2 + 1024L * 4096 * 2;
constexpr long OFF_WHEAD= OFF_WEMB + 1024L * 64 * 2;
constexpr long OFF_SMP  = OFF_WHEAD+ 256L * 1024 * 2;
constexpr long OFF_X    = OFF_SMP  + (long)ME * 64 * 2;
constexpr long OFF_H    = OFF_X    + (long)MR * E * 4;
constexpr long OFF_Q    = OFF_H    + (long)MR * E * 2;
constexpr long OFF_K    = OFF_Q    + 256L * SPAD * HD * 2;
constexpr long OFF_VT   = OFF_K    + 256L * SPAD * HD * 2;
constexpr long OFF_O    = OFF_VT   + 256L * SPAD * HD * 2;   // a1 overlays o
constexpr long OFF_HF   = OFF_O    + (long)MR * FF * 2;
constexpr long WS_NEED  = OFF_HF   + 256L * 1024 * 2;        // ~196 MB

extern "C" void kernel_launch(void* const* d_in, const int* in_sizes, int n_in,
                              void* d_out, int out_size, void* d_ws, size_t ws_size,
                              hipStream_t stream) {
  if (ws_size < (size_t)WS_NEED) return;

  const float* sample = (const float*)d_in[0];
  const float* W_emb  = (const float*)d_in[1];
  const float* b_emb  = (const float*)d_in[2];
  const float* pos    = (const float*)d_in[3];
  const float* regs   = (const float*)d_in[4];
  const float* ln1_s  = (const float*)d_in[5];
  const float* ln1_b  = (const float*)d_in[6];
  const float* W_qkv  = (const float*)d_in[7];
  const float* b_qkv  = (const float*)d_in[8];
  const float* W_o    = (const float*)d_in[9];
  const float* b_o    = (const float*)d_in[10];
  const float* ln2_s  = (const float*)d_in[11];
  const float* ln2_b  = (const float*)d_in[12];
  const float* W_fc1  = (const float*)d_in[13];
  const float* b_fc1  = (const float*)d_in[14];
  const float* W_fc2  = (const float*)d_in[15];
  const float* b_fc2  = (const float*)d_in[16];
  const float* lnf_s  = (const float*)d_in[17];
  const float* lnf_b  = (const float*)d_in[18];
  const float* W_head = (const float*)d_in[19];
  const float* b_head = (const float*)d_in[20];

  char* w = (char*)d_ws;
  u16* wqkvT = (u16*)(w + OFF_WQKV);
  u16* woT   = (u16*)(w + OFF_WO);
  u16* wfc1T = (u16*)(w + OFF_WFC1);
  u16* wfc2T = (u16*)(w + OFF_WFC2);
  u16* wembT = (u16*)(w + OFF_WEMB);
  u16* wheadT= (u16*)(w + OFF_WHEAD);
  u16* smp   = (u16*)(w + OFF_SMP);
  float* x   = (float*)(w + OFF_X);
  u16* h     = (u16*)(w + OFF_H);
  u16* qp    = (u16*)(w + OFF_Q);
  u16* kp    = (u16*)(w + OFF_K);
  u16* vtp   = (u16*)(w + OFF_VT);
  u16* o     = (u16*)(w + OFF_O);
  u16* a1    = (u16*)(w + OFF_O);   // overlay: o dead when a1 live
  u16* hf    = (u16*)(w + OFF_HF);

  // ---- one-time prep ----
  wtrans<<<dim3(32, 2, 1), 256, 0, stream>>>(W_emb,  wembT, 64, 1024);
  wtrans<<<dim3(8, 32, 1), 256, 0, stream>>>(W_head, wheadT, 1024, 256);
  cvt_bf<<<dim3(512), 256, 0, stream>>>(sample, smp, (long)ME * 64);
  zero_k<<<dim3(2048), 256, 0, stream>>>((float4*)qp, (3L * 256 * SPAD * HD * 2) / 16);

  // ---- embed + registers ----
  {
    GA g{}; g.A = smp; g.Bt = wembT; g.K = 64; g.lda = 64; g.ldb = 64;
    g.Nrows = E; g.bias = b_emb; g.pos = pos; g.fout = x;
    gemm_bt<M_EMBED, 64><<<dim3(16, 64, 1), 256, 0, stream>>>(g);
  }
  reg_copy<<<dim3(256), 256, 0, stream>>>(regs, x);

  for (int L = 0; L < DEPTH; ++L) {
    // merged per-layer weight transpose (1 launch for qkv/o/fc1/fc2)
    {
      WT4 a;
      a.s[0] = W_qkv + (long)L * 1024 * 3072; a.d[0] = wqkvT; a.R[0] = 1024; a.C[0] = 3072; a.tx[0] = 96;  a.st[0] = 0;
      a.s[1] = W_o   + (long)L * 1024 * 1024; a.d[1] = woT;   a.R[1] = 1024; a.C[1] = 1024; a.tx[1] = 32;  a.st[1] = 3072;
      a.s[2] = W_fc1 + (long)L * 1024 * 4096; a.d[2] = wfc1T; a.R[2] = 1024; a.C[2] = 4096; a.tx[2] = 128; a.st[2] = 4096;
      a.s[3] = W_fc2 + (long)L * 4096 * 1024; a.d[3] = wfc2T; a.R[3] = 4096; a.C[3] = 1024; a.tx[3] = 32;  a.st[3] = 8192;
      wtrans4<<<dim3(12288), 256, 0, stream>>>(a);
    }

    ln_k<<<dim3(MR), 256, 0, stream>>>(x, ln1_s + L * E, ln1_b + L * E, h, 0);
    {
      GA g{}; g.A = h; g.Bt = wqkvT;
      g.K = 1024; g.lda = 1024; g.ldb = 1024; g.Nrows = 3072;
      g.bias = b_qkv + L * 3072; g.qp = qp; g.kp = kp; g.vtp = vtp;
      gemm_bt<M_QKV, 128><<<dim3(24, 66, 1), 256, 0, stream>>>(g);
    }
    flash_k<<<dim3(5, 256, 1), 256, 0, stream>>>(qp, kp, vtp, o);
    {
      GA g{}; g.A = o; g.Bt = woT;
      g.K = 1024; g.lda = 1024; g.ldb = 1024; g.Nrows = 1024; g.ldc = 1024;
      g.bias = b_o + L * E; g.fout = x;
      gemm_bt<M_OPROJ, 128><<<dim3(8, 66, 1), 256, 0, stream>>>(g);
    }
    ln_k<<<dim3(MR), 256, 0, stream>>>(x, ln2_s + L * E, ln2_b + L * E, h, 0);
    {
      GA g{}; g.A = h; g.Bt = wfc1T;
      g.K = 1024; g.lda = 1024; g.ldb = 1024; g.Nrows = 4096; g.ldc = 4096;
      g.bias = b_fc1 + L * FF; g.bout = a1;
      gemm_bt<M_FC1, 128><<<dim3(32, 66, 1), 256, 0, stream>>>(g);
    }
    {
      GA g{}; g.A = a1; g.Bt = wfc2T;
      g.K = 4096; g.lda = 4096; g.ldb = 4096; g.Nrows = 1024; g.ldc = 1024;
      g.bias = b_fc2 + L * E; g.fout = x;
      gemm_bt<M_FC2, 128><<<dim3(8, 66, 1), 256, 0, stream>>>(g);
    }
  }

  ln_k<<<dim3(256), 256, 0, stream>>>(x, lnf_s, lnf_b, hf, 1);
  {
    GA g{}; g.A = hf; g.Bt = wheadT; g.K = 1024; g.lda = 1024; g.ldb = 1024;
    g.Nrows = LAT; g.ldc = LAT; g.bias = b_head; g.fout = (float*)d_out;
    gemm_bt<M_HEAD, 128><<<dim3(2, 2, 1), 256, 0, stream>>>(g);
  }
}

// Round 15
// 3882.071 us; speedup vs baseline: 1.3097x; 1.0852x over previous
//
#include <hip/hip_runtime.h>
#include <hip/hip_bf16.h>

// RegisterEncoder: 8-layer pre-LN transformer, bf16 MFMA GEMMs, f32 residual.
// Round 15: exact revert to R10 (best proven: 3886us). R11-R14 falsified, via
// counters: LDS-BW, B-reg-streaming, 8-wave tiles, BN=256, 2x2 supertiling --
// all regressed vs the 4-wave 128^2 / 3-buffer / counted-vmcnt / swizzled
// structure. Only change vs R10: head GEMM BN=64 grid(4,2) (proven path).
// zero_k kept: pad rows must be finite on first call (0*pad=0 in flash PV).

typedef unsigned short u16;
typedef __attribute__((ext_vector_type(4))) float f32x4;
typedef __attribute__((ext_vector_type(8))) __bf16 bf16x8;

#define DEV static __device__ __forceinline__

constexpr int Bb = 16, Tt = 512, E = 1024, HD = 64, NHd = 16;
constexpr int DEPTH = 8, NREG = 16, LAT = 256, FF = 4096;
constexpr int S = Tt + NREG;   // 528
constexpr int SPAD = 576;      // padded attention seq (9 x 64)
constexpr int MR = Bb * S;     // 8448
constexpr int ME = Bb * Tt;    // 8192

DEV u16 f2bf(float f) {
  unsigned u = __builtin_bit_cast(unsigned, f);
  u += 0x7fffu + ((u >> 16) & 1u);
  return (u16)(u >> 16);
}
DEV float bf2f(u16 h) { return __builtin_bit_cast(float, (unsigned)h << 16); }

DEV void gll16(const u16* g, u16* l) {
  __builtin_amdgcn_global_load_lds((const __attribute__((address_space(1))) void*)g,
                                   (__attribute__((address_space(3))) void*)l, 16, 0, 0);
}

// ---------------- GEMM: C[M,N] = A[M,K](bf16) * Bt[N,K]^T(bf16) ----------------
enum { M_EMBED, M_QKV, M_OPROJ, M_FC1, M_FC2, M_HEAD };

struct GA {
  const u16* A; const u16* Bt;
  int K, lda, ldb, Nrows, ldc;
  const float* bias; const float* pos;
  float* fout; u16* bout;
  u16 *qp, *kp, *vtp;
};

template<int MODE, int BN>
__global__ __launch_bounds__(256)
void gemm_bt(GA g) {
  constexpr int NI = BN / 32;                  // B fragments per wave
  __shared__ __align__(16) u16 As[3][128 * 32];
  __shared__ __align__(16) u16 Bs[3][BN * 32];
  const int tid = threadIdx.x;
  const u16* A  = g.A;
  const u16* Bt = g.Bt;

  // bijective XCD swizzle (m204): consecutive local ids share the A-panel
  int tM, tN;
  {
    const int nwg = gridDim.x * gridDim.y;
    int flat = blockIdx.y * gridDim.x + blockIdx.x;
    const int q = nwg >> 3, r = nwg & 7;
    const int xcd = flat & 7, loc = flat >> 3;
    flat = (xcd < r ? xcd * (q + 1) : r * (q + 1) + (xcd - r) * q) + loc;
    tM = flat / gridDim.x; tN = flat % gridDim.x;
  }

  const int lane = tid & 63, wid = tid >> 6;
  const int wr = wid >> 1, wc = wid & 1;       // 2x2 waves
  const int fr = lane & 15, fg = lane >> 4;

  const int arow = tM * 128 + (tid >> 2);
  int br0 = tN * BN + (tid >> 2);
  if (br0 > g.Nrows - 1) br0 = g.Nrows - 1;
  int br1 = tN * BN + 64 + (tid >> 2);
  if (br1 > g.Nrows - 1) br1 = g.Nrows - 1;
  // pre-swizzled SOURCE chunk (both-sides swizzle, rule #21)
  const int kseg = ((tid & 3) ^ ((tid >> 3) & 3)) * 8;
  const int woff = (tid & 192) * 8;            // wave-uniform LDS offset (elems)

  const u16* ag0 = A  + (long)arow        * g.lda + kseg;
  const u16* ag1 = A  + (long)(arow + 64) * g.lda + kseg;
  const u16* bg0 = Bt + (long)br0         * g.ldb + kseg;
  const u16* bg1 = Bt + (long)br1         * g.ldb + kseg;

  f32x4 acc[4][NI];
#pragma unroll
  for (int i = 0; i < 4; ++i)
#pragma unroll
    for (int j = 0; j < NI; ++j) acc[i][j] = f32x4{0.f, 0.f, 0.f, 0.f};

#define STAGE(KT, BUF) do {                                   \
    const int _k0 = (KT) << 5;                                \
    gll16(ag0 + _k0, &As[BUF][woff]);                         \
    gll16(ag1 + _k0, &As[BUF][woff + 2048]);                  \
    gll16(bg0 + _k0, &Bs[BUF][woff]);                         \
    if (BN == 128) gll16(bg1 + _k0, &Bs[BUF][woff + 2048]);   \
  } while (0)

  const int nk = g.K >> 5;
  STAGE(0, 0);
  if (nk > 1) STAGE(1, 1);

  // read-side swizzle: physical chunk for logical fg of row (..+fr)
  const int rsw = (fg ^ ((fr >> 1) & 3)) * 8;
  constexpr int LPS = (BN == 128) ? 4 : 3;     // loads per stage

  for (int kt = 0; kt < nk; ++kt) {
    const int cur = kt % 3;
    if (kt < nk - 1) {
      asm volatile("s_waitcnt vmcnt(%0)" :: "i"(LPS) : "memory");
    } else {
      asm volatile("s_waitcnt vmcnt(0)" ::: "memory");
    }
    __builtin_amdgcn_sched_barrier(0);
    __builtin_amdgcn_s_barrier();
    __builtin_amdgcn_sched_barrier(0);
    if (kt + 2 < nk) STAGE(kt + 2, (kt + 2) % 3);

    bf16x8 af[4], bfr[NI];
#pragma unroll
    for (int mi = 0; mi < 4; ++mi)
      af[mi] = *(const bf16x8*)&As[cur][(wr * 64 + mi * 16 + fr) * 32 + rsw];
#pragma unroll
    for (int ni = 0; ni < NI; ++ni)
      bfr[ni] = *(const bf16x8*)&Bs[cur][(wc * (BN / 2) + ni * 16 + fr) * 32 + rsw];
    __builtin_amdgcn_s_setprio(1);
#pragma unroll
    for (int mi = 0; mi < 4; ++mi)
#pragma unroll
      for (int ni = 0; ni < NI; ++ni)
        acc[mi][ni] = __builtin_amdgcn_mfma_f32_16x16x32_bf16(af[mi], bfr[ni], acc[mi][ni], 0, 0, 0);
    __builtin_amdgcn_s_setprio(0);
  }
#undef STAGE

#pragma unroll
  for (int mi = 0; mi < 4; ++mi)
#pragma unroll
    for (int ni = 0; ni < NI; ++ni)
#pragma unroll
      for (int j = 0; j < 4; ++j) {
        const int row = tM * 128 + wr * 64 + mi * 16 + fg * 4 + j;
        const int col = tN * BN + wc * (BN / 2) + ni * 16 + fr;
        float v = acc[mi][ni][j];
        if (MODE == M_EMBED) {
          const int b = row >> 9, t = row & 511;
          v += g.bias[col] + g.pos[(long)t * E + col];
          g.fout[((long)(b * S + t)) * E + col] = v;
        } else if (MODE == M_QKV) {
          const int b = row / S, s = row - b * S;
          v += g.bias[col];
          const int part = col >> 10, c = col & 1023;
          const int hh = c >> 6, d = c & 63;
          const u16 bf = f2bf(v);
          if (part == 0)      g.qp [((long)((b * NHd + hh) * SPAD + s)) * HD + d] = bf;
          else if (part == 1) g.kp [((long)((b * NHd + hh) * SPAD + s)) * HD + d] = bf;
          else                g.vtp[((long)((b * NHd + hh) * HD   + d)) * SPAD + s] = bf;
        } else if (MODE == M_OPROJ || MODE == M_FC2) {
          const long idx = (long)row * g.ldc + col;
          g.fout[idx] += v + g.bias[col];
        } else if (MODE == M_FC1) {
          v += g.bias[col];
          const float z = 0.7978845608028654f * (v + 0.044715f * v * v * v);
          const float e = __expf(2.f * z);
          const float th = 1.f - 2.f / (e + 1.f);   // tanh(z), overflow-safe
          g.bout[(long)row * g.ldc + col] = f2bf(0.5f * v * (1.f + th));
        } else if (MODE == M_HEAD) {
          g.fout[(long)row * g.ldc + col] = v + g.bias[col];
        }
      }
}

// ---------------- fused flash attention, QBLK=128 (R10, verified) ----------------
__global__ __launch_bounds__(256)
void flash_k(const u16* __restrict__ q, const u16* __restrict__ k,
             const u16* __restrict__ vt, u16* __restrict__ o) {
  __shared__ __align__(16) u16 Ks[2][64 * 64];
  __shared__ __align__(16) u16 Vs[2][64 * 64];   // VT tile: [d][kv]
  __shared__ __align__(16) u16 Ps[4 * 32 * 64];
  const int tid = threadIdx.x;
  const int lane = tid & 63, w = tid >> 6;
  const int fr = lane & 15, fg = lane >> 4;

  // XCD swizzle: 1280 blocks % 8 == 0; contiguous bh chunks per XCD
  int flat = blockIdx.y * 5 + blockIdx.x;
  flat = (flat & 7) * 160 + (flat >> 3);
  const int bh = flat / 5, qt = flat % 5;
  const int q0 = qt * 128;

  bf16x8 qf[2][2];
#pragma unroll
  for (int ms = 0; ms < 2; ++ms) {
    int qr = q0 + w * 32 + ms * 16 + fr;
    if (qr > SPAD - 1) qr = SPAD - 1;
    const u16* qrow = q + ((long)bh * SPAD + qr) * HD;
    qf[ms][0] = *(const bf16x8*)(qrow + fg * 8);
    qf[ms][1] = *(const bf16x8*)(qrow + 32 + fg * 8);
  }

  const int srow = lane >> 3;
  const int sseg = (((lane & 7) ^ (srow & 7)) * 8);
  const u16* kg = k  + ((long)bh * SPAD + w * 16 + srow) * HD + sseg;
  const u16* vg = vt + ((long)(bh * HD + w * 16 + srow)) * SPAD + sseg;

#define STAGE_F(KT, BUF) do {                                       \
    gll16(kg + (KT) * 64 * HD,          &Ks[BUF][w * 16 * HD]);     \
    gll16(kg + (KT) * 64 * HD + 8 * HD, &Ks[BUF][w * 16 * HD + 8 * HD]); \
    gll16(vg + (KT) * 64,               &Vs[BUF][w * 16 * HD]);     \
    gll16(vg + (KT) * 64 + 8 * SPAD,    &Vs[BUF][w * 16 * HD + 8 * HD]); \
  } while (0)

  const int frm = fr & 7;

  float m[2][4], lsum[2][4]; f32x4 oa[2][4];
#pragma unroll
  for (int ms = 0; ms < 2; ++ms)
#pragma unroll
    for (int j = 0; j < 4; ++j) { m[ms][j] = -1e30f; lsum[ms][j] = 0.f; }
#pragma unroll
  for (int ms = 0; ms < 2; ++ms)
#pragma unroll
    for (int n = 0; n < 4; ++n) oa[ms][n] = f32x4{0.f, 0.f, 0.f, 0.f};

  const int nt = (qt < 4) ? 8 : 9;
  STAGE_F(0, 0);
  for (int kt = 0; kt < nt; ++kt) {
    const int cur = kt & 1;
    asm volatile("s_waitcnt vmcnt(0)" ::: "memory");
    __builtin_amdgcn_sched_barrier(0);
    __builtin_amdgcn_s_barrier();
    __builtin_amdgcn_sched_barrier(0);
    if (kt + 1 < nt) STAGE_F(kt + 1, cur ^ 1);

    f32x4 sfr[2][4];
#pragma unroll
    for (int n = 0; n < 4; ++n) {
      const bf16x8 kf0 = *(const bf16x8*)&Ks[cur][(n * 16 + fr) * HD + ((fg ^ frm) * 8)];
      const bf16x8 kf1 = *(const bf16x8*)&Ks[cur][(n * 16 + fr) * HD + (((fg + 4) ^ frm) * 8)];
#pragma unroll
      for (int ms = 0; ms < 2; ++ms) {
        sfr[ms][n] = __builtin_amdgcn_mfma_f32_16x16x32_bf16(qf[ms][0], kf0, f32x4{0.f,0.f,0.f,0.f}, 0, 0, 0);
        sfr[ms][n] = __builtin_amdgcn_mfma_f32_16x16x32_bf16(qf[ms][1], kf1, sfr[ms][n], 0, 0, 0);
      }
    }
    float p[2][4][4];
#pragma unroll
    for (int ms = 0; ms < 2; ++ms)
#pragma unroll
      for (int j = 0; j < 4; ++j) {
        const int qg = q0 + w * 32 + ms * 16 + fg * 4 + j;
        const int vlim = qg < Tt ? Tt : qg + 1;
#pragma unroll
        for (int n = 0; n < 4; ++n) {
          const int col = kt * 64 + n * 16 + fr;
          p[ms][n][j] = (col < vlim) ? sfr[ms][n][j] * 0.125f : -1e30f;
        }
      }
#pragma unroll
    for (int ms = 0; ms < 2; ++ms)
#pragma unroll
      for (int j = 0; j < 4; ++j) {
        float pm = fmaxf(fmaxf(p[ms][0][j], p[ms][1][j]), fmaxf(p[ms][2][j], p[ms][3][j]));
#pragma unroll
        for (int msk = 1; msk <= 8; msk <<= 1) pm = fmaxf(pm, __shfl_xor(pm, msk));
        const float mn = fmaxf(m[ms][j], pm);
        const float corr = __expf(m[ms][j] - mn);
        m[ms][j] = mn;
        float rs = 0.f;
#pragma unroll
        for (int n = 0; n < 4; ++n) { const float e = __expf(p[ms][n][j] - mn); p[ms][n][j] = e; rs += e; }
#pragma unroll
        for (int msk = 1; msk <= 8; msk <<= 1) rs += __shfl_xor(rs, msk);
        lsum[ms][j] = lsum[ms][j] * corr + rs;
#pragma unroll
        for (int n = 0; n < 4; ++n) oa[ms][n][j] *= corr;
      }
#pragma unroll
    for (int ms = 0; ms < 2; ++ms)
#pragma unroll
      for (int j = 0; j < 4; ++j) {
        const int r = ms * 16 + fg * 4 + j;
#pragma unroll
        for (int n = 0; n < 4; ++n) {
          const int gr = 2 * n + (fr >> 3);
          Ps[w * 2048 + r * 64 + ((gr ^ (r & 7)) * 8) + frm] = f2bf(p[ms][n][j]);
        }
      }
    asm volatile("s_waitcnt lgkmcnt(0)" ::: "memory");
    __builtin_amdgcn_sched_barrier(0);
    bf16x8 pf[2][2];
#pragma unroll
    for (int ms = 0; ms < 2; ++ms) {
      pf[ms][0] = *(const bf16x8*)&Ps[w * 2048 + (ms * 16 + fr) * 64 + ((fg ^ frm) * 8)];
      pf[ms][1] = *(const bf16x8*)&Ps[w * 2048 + (ms * 16 + fr) * 64 + (((fg + 4) ^ frm) * 8)];
    }
#pragma unroll
    for (int n = 0; n < 4; ++n) {
      const bf16x8 vf0 = *(const bf16x8*)&Vs[cur][(n * 16 + fr) * HD + ((fg ^ frm) * 8)];
      const bf16x8 vf1 = *(const bf16x8*)&Vs[cur][(n * 16 + fr) * HD + (((fg + 4) ^ frm) * 8)];
#pragma unroll
      for (int ms = 0; ms < 2; ++ms) {
        oa[ms][n] = __builtin_amdgcn_mfma_f32_16x16x32_bf16(pf[ms][0], vf0, oa[ms][n], 0, 0, 0);
        oa[ms][n] = __builtin_amdgcn_mfma_f32_16x16x32_bf16(pf[ms][1], vf1, oa[ms][n], 0, 0, 0);
      }
    }
  }
#undef STAGE_F

  const int b = bh >> 4, hh = bh & 15;
#pragma unroll
  for (int ms = 0; ms < 2; ++ms)
#pragma unroll
    for (int j = 0; j < 4; ++j) {
      const int qg = q0 + w * 32 + ms * 16 + fg * 4 + j;
      if (qg < S) {
        const float inv = 1.f / lsum[ms][j];
#pragma unroll
        for (int n = 0; n < 4; ++n)
          o[((long)(b * S + qg)) * E + hh * HD + n * 16 + fr] = f2bf(oa[ms][n][j] * inv);
      }
    }
}

// ---------------- LayerNorm ----------------
__global__ __launch_bounds__(256)
void ln_k(const float* __restrict__ x, const float* __restrict__ sc,
          const float* __restrict__ bi, u16* __restrict__ out, int gather) {
  const int r = blockIdx.x;
  const int srow = gather ? ((r >> 4) * S + Tt + (r & 15)) : r;
  const float4 v = ((const float4*)(x + (long)srow * E))[threadIdx.x];
  float s = v.x + v.y + v.z + v.w;
  float q = v.x * v.x + v.y * v.y + v.z * v.z + v.w * v.w;
#pragma unroll
  for (int o = 32; o; o >>= 1) { s += __shfl_down(s, o); q += __shfl_down(q, o); }
  __shared__ float ps[8];
  if ((threadIdx.x & 63) == 0) { ps[threadIdx.x >> 6] = s; ps[4 + (threadIdx.x >> 6)] = q; }
  __syncthreads();
  s = ps[0] + ps[1] + ps[2] + ps[3];
  q = ps[4] + ps[5] + ps[6] + ps[7];
  const float mean = s * (1.f / E);
  const float rs = rsqrtf(q * (1.f / E) - mean * mean + 1e-5f);
  const int c = threadIdx.x * 4;
  ushort4 o4;
  o4.x = f2bf((v.x - mean) * rs * sc[c + 0] + bi[c + 0]);
  o4.y = f2bf((v.y - mean) * rs * sc[c + 1] + bi[c + 1]);
  o4.z = f2bf((v.z - mean) * rs * sc[c + 2] + bi[c + 2]);
  o4.w = f2bf((v.w - mean) * rs * sc[c + 3] + bi[c + 3]);
  ((ushort4*)(out + (long)r * E))[threadIdx.x] = o4;
}

// ---------------- transpose f32[R,C] -> bf16[C,R] ----------------
__global__ __launch_bounds__(256)
void wtrans(const float* __restrict__ src, u16* __restrict__ dst, int R, int C) {
  __shared__ float t[32][33];
  const int c0 = blockIdx.x * 32, r0 = blockIdx.y * 32;
  const int tx = threadIdx.x & 31, ty = threadIdx.x >> 5;
#pragma unroll
  for (int i = 0; i < 32; i += 8) t[ty + i][tx] = src[(long)(r0 + ty + i) * C + c0 + tx];
  __syncthreads();
#pragma unroll
  for (int i = 0; i < 32; i += 8) dst[(long)(c0 + ty + i) * R + r0 + tx] = f2bf(t[tx][ty + i]);
}

// ---------------- merged per-layer weight transpose (4 weights, 1 launch) ----
struct WT4 {
  const float* s[4]; u16* d[4];
  int R[4], C[4], tx[4], st[4];
};
__global__ __launch_bounds__(256)
void wtrans4(WT4 a) {
  const int bid = blockIdx.x;
  const int wsel = (bid >= a.st[1]) + (bid >= a.st[2]) + (bid >= a.st[3]);
  const int t = bid - a.st[wsel];
  const int c0 = (t % a.tx[wsel]) * 32, r0 = (t / a.tx[wsel]) * 32;
  const float* src = a.s[wsel]; u16* dst = a.d[wsel];
  const int R = a.R[wsel], C = a.C[wsel];
  __shared__ float tt[32][33];
  const int tx = threadIdx.x & 31, ty = threadIdx.x >> 5;
#pragma unroll
  for (int i = 0; i < 32; i += 8) tt[ty + i][tx] = src[(long)(r0 + ty + i) * C + c0 + tx];
  __syncthreads();
#pragma unroll
  for (int i = 0; i < 32; i += 8) dst[(long)(c0 + ty + i) * R + r0 + tx] = f2bf(tt[tx][ty + i]);
}

// ---------------- small utility kernels ----------------
__global__ void cvt_bf(const float* __restrict__ in, u16* __restrict__ out, long n) {
  const long i = ((long)blockIdx.x * blockDim.x + threadIdx.x) * 4;
  if (i >= n) return;
  const float4 v = *(const float4*)(in + i);
  ushort4 o; o.x = f2bf(v.x); o.y = f2bf(v.y); o.z = f2bf(v.z); o.w = f2bf(v.w);
  *(ushort4*)(out + i) = o;
}

__global__ void zero_k(float4* p, long n) {
  long i = (long)blockIdx.x * blockDim.x + threadIdx.x;
  const long st = (long)gridDim.x * blockDim.x;
  const float4 z = make_float4(0.f, 0.f, 0.f, 0.f);
  for (; i < n; i += st) p[i] = z;
}

__global__ void reg_copy(const float* __restrict__ regs, float* __restrict__ x) {
  const int b = blockIdx.x >> 4, r = blockIdx.x & 15;
  const float4* sp = (const float4*)(regs + (long)r * E);
  float4* dp = (float4*)(x + ((long)(b * S + Tt + r)) * E);
  dp[threadIdx.x] = sp[threadIdx.x];
}

// ---------------- workspace layout (bytes, all 16-aligned) ----------------
constexpr long OFF_WQKV = 0L;                                // per-layer, reused
constexpr long OFF_WO   = OFF_WQKV + 3072L * 1024 * 2;
constexpr long OFF_WFC1 = OFF_WO   + 1024L * 1024 * 2;
constexpr long OFF_WFC2 = OFF_WFC1 + 4096L * 1024 * 2;
constexpr long OFF_WEMB = OFF_WFC2 + 1024L * 4096 * 2;
constexpr long OFF_WHEAD= OFF_WEMB + 1024L * 64 * 2;
constexpr long OFF_SMP  = OFF_WHEAD+ 256L * 1024 * 2;
constexpr long OFF_X    = OFF_SMP  + (long)ME * 64 * 2;
constexpr long OFF_H    = OFF_X    + (long)MR * E * 4;
constexpr long OFF_Q    = OFF_H    + (long)MR * E * 2;
constexpr long OFF_K    = OFF_Q    + 256L * SPAD * HD * 2;
constexpr long OFF_VT   = OFF_K    + 256L * SPAD * HD * 2;
constexpr long OFF_O    = OFF_VT   + 256L * SPAD * HD * 2;   // a1 overlays o
constexpr long OFF_HF   = OFF_O    + (long)MR * FF * 2;
constexpr long WS_NEED  = OFF_HF   + 256L * 1024 * 2;        // ~196 MB

extern "C" void kernel_launch(void* const* d_in, const int* in_sizes, int n_in,
                              void* d_out, int out_size, void* d_ws, size_t ws_size,
                              hipStream_t stream) {
  if (ws_size < (size_t)WS_NEED) return;

  const float* sample = (const float*)d_in[0];
  const float* W_emb  = (const float*)d_in[1];
  const float* b_emb  = (const float*)d_in[2];
  const float* pos    = (const float*)d_in[3];
  const float* regs   = (const float*)d_in[4];
  const float* ln1_s  = (const float*)d_in[5];
  const float* ln1_b  = (const float*)d_in[6];
  const float* W_qkv  = (const float*)d_in[7];
  const float* b_qkv  = (const float*)d_in[8];
  const float* W_o    = (const float*)d_in[9];
  const float* b_o    = (const float*)d_in[10];
  const float* ln2_s  = (const float*)d_in[11];
  const float* ln2_b  = (const float*)d_in[12];
  const float* W_fc1  = (const float*)d_in[13];
  const float* b_fc1  = (const float*)d_in[14];
  const float* W_fc2  = (const float*)d_in[15];
  const float* b_fc2  = (const float*)d_in[16];
  const float* lnf_s  = (const float*)d_in[17];
  const float* lnf_b  = (const float*)d_in[18];
  const float* W_head = (const float*)d_in[19];
  const float* b_head = (const float*)d_in[20];

  char* w = (char*)d_ws;
  u16* wqkvT = (u16*)(w + OFF_WQKV);
  u16* woT   = (u16*)(w + OFF_WO);
  u16* wfc1T = (u16*)(w + OFF_WFC1);
  u16* wfc2T = (u16*)(w + OFF_WFC2);
  u16* wembT = (u16*)(w + OFF_WEMB);
  u16* wheadT= (u16*)(w + OFF_WHEAD);
  u16* smp   = (u16*)(w + OFF_SMP);
  float* x   = (float*)(w + OFF_X);
  u16* h     = (u16*)(w + OFF_H);
  u16* qp    = (u16*)(w + OFF_Q);
  u16* kp    = (u16*)(w + OFF_K);
  u16* vtp   = (u16*)(w + OFF_VT);
  u16* o     = (u16*)(w + OFF_O);
  u16* a1    = (u16*)(w + OFF_O);   // overlay: o dead when a1 live
  u16* hf    = (u16*)(w + OFF_HF);

  // ---- one-time prep ----
  wtrans<<<dim3(32, 2, 1), 256, 0, stream>>>(W_emb,  wembT, 64, 1024);
  wtrans<<<dim3(8, 32, 1), 256, 0, stream>>>(W_head, wheadT, 1024, 256);
  cvt_bf<<<dim3(512), 256, 0, stream>>>(sample, smp, (long)ME * 64);
  zero_k<<<dim3(2048), 256, 0, stream>>>((float4*)qp, (3L * 256 * SPAD * HD * 2) / 16);

  // ---- embed + registers ----
  {
    GA g{}; g.A = smp; g.Bt = wembT; g.K = 64; g.lda = 64; g.ldb = 64;
    g.Nrows = E; g.bias = b_emb; g.pos = pos; g.fout = x;
    gemm_bt<M_EMBED, 64><<<dim3(16, 64, 1), 256, 0, stream>>>(g);
  }
  reg_copy<<<dim3(256), 256, 0, stream>>>(regs, x);

  for (int L = 0; L < DEPTH; ++L) {
    // merged per-layer weight transpose (1 launch for qkv/o/fc1/fc2)
    {
      WT4 a;
      a.s[0] = W_qkv + (long)L * 1024 * 3072; a.d[0] = wqkvT; a.R[0] = 1024; a.C[0] = 3072; a.tx[0] = 96;  a.st[0] = 0;
      a.s[1] = W_o   + (long)L * 1024 * 1024; a.d[1] = woT;   a.R[1] = 1024; a.C[1] = 1024; a.tx[1] = 32;  a.st[1] = 3072;
      a.s[2] = W_fc1 + (long)L * 1024 * 4096; a.d[2] = wfc1T; a.R[2] = 1024; a.C[2] = 4096; a.tx[2] = 128; a.st[2] = 4096;
      a.s[3] = W_fc2 + (long)L * 4096 * 1024; a.d[3] = wfc2T; a.R[3] = 4096; a.C[3] = 1024; a.tx[3] = 32;  a.st[3] = 8192;
      wtrans4<<<dim3(12288), 256, 0, stream>>>(a);
    }

    ln_k<<<dim3(MR), 256, 0, stream>>>(x, ln1_s + L * E, ln1_b + L * E, h, 0);
    {
      GA g{}; g.A = h; g.Bt = wqkvT;
      g.K = 1024; g.lda = 1024; g.ldb = 1024; g.Nrows = 3072;
      g.bias = b_qkv + L * 3072; g.qp = qp; g.kp = kp; g.vtp = vtp;
      gemm_bt<M_QKV, 128><<<dim3(24, 66, 1), 256, 0, stream>>>(g);
    }
    flash_k<<<dim3(5, 256, 1), 256, 0, stream>>>(qp, kp, vtp, o);
    {
      GA g{}; g.A = o; g.Bt = woT;
      g.K = 1024; g.lda = 1024; g.ldb = 1024; g.Nrows = 1024; g.ldc = 1024;
      g.bias = b_o + L * E; g.fout = x;
      gemm_bt<M_OPROJ, 128><<<dim3(8, 66, 1), 256, 0, stream>>>(g);
    }
    ln_k<<<dim3(MR), 256, 0, stream>>>(x, ln2_s + L * E, ln2_b + L * E, h, 0);
    {
      GA g{}; g.A = h; g.Bt = wfc1T;
      g.K = 1024; g.lda = 1024; g.ldb = 1024; g.Nrows = 4096; g.ldc = 4096;
      g.bias = b_fc1 + L * FF; g.bout = a1;
      gemm_bt<M_FC1, 128><<<dim3(32, 66, 1), 256, 0, stream>>>(g);
    }
    {
      GA g{}; g.A = a1; g.Bt = wfc2T;
      g.K = 4096; g.lda = 4096; g.ldb = 4096; g.Nrows = 1024; g.ldc = 1024;
      g.bias = b_fc2 + L * E; g.fout = x;
      gemm_bt<M_FC2, 128><<<dim3(8, 66, 1), 256, 0, stream>>>(g);
    }
  }

  ln_k<<<dim3(256), 256, 0, stream>>>(x, lnf_s, lnf_b, hf, 1);
  {
    GA g{}; g.A = hf; g.Bt = wheadT; g.K = 1024; g.lda = 1024; g.ldb = 1024;
    g.Nrows = LAT; g.ldc = LAT; g.bias = b_head; g.fout = (float*)d_out;
    gemm_bt<M_HEAD, 64><<<dim3(4, 2, 1), 256, 0, stream>>>(g);
  }
}

// Round 16
// 3831.944 us; speedup vs baseline: 1.3269x; 1.0131x over previous
//
#include <hip/hip_runtime.h>
#include <hip/hip_bf16.h>

// RegisterEncoder: 8-layer pre-LN transformer, bf16 MFMA GEMMs, f32 residual.
// Round 16: discriminate fc2's last open theory (grid-starvation vs fabric).
// fc2 -> split-K x2 (grid z=2, 1056 blocks = 4.1/CU, SAME 128^2 pipeline),
// non-atomic bf16 partials into dead kp/vtp buffers, fused reduce+LN1 kernel
// (also removes 7 ln_k launches). Everything else identical to proven R15.

typedef unsigned short u16;
typedef __attribute__((ext_vector_type(4))) float f32x4;
typedef __attribute__((ext_vector_type(8))) __bf16 bf16x8;

#define DEV static __device__ __forceinline__

constexpr int Bb = 16, Tt = 512, E = 1024, HD = 64, NHd = 16;
constexpr int DEPTH = 8, NREG = 16, LAT = 256, FF = 4096;
constexpr int S = Tt + NREG;   // 528
constexpr int SPAD = 576;      // padded attention seq (9 x 64)
constexpr int MR = Bb * S;     // 8448
constexpr int ME = Bb * Tt;    // 8192

DEV u16 f2bf(float f) {
  unsigned u = __builtin_bit_cast(unsigned, f);
  u += 0x7fffu + ((u >> 16) & 1u);
  return (u16)(u >> 16);
}
DEV float bf2f(u16 h) { return __builtin_bit_cast(float, (unsigned)h << 16); }

DEV void gll16(const u16* g, u16* l) {
  __builtin_amdgcn_global_load_lds((const __attribute__((address_space(1))) void*)g,
                                   (__attribute__((address_space(3))) void*)l, 16, 0, 0);
}

// ---------------- GEMM: C[M,N] = A[M,K](bf16) * Bt[N,K]^T(bf16) ----------------
enum { M_EMBED, M_QKV, M_OPROJ, M_FC1, M_FC2, M_HEAD };

struct GA {
  const u16* A; const u16* Bt;
  int K, Kc, lda, ldb, Nrows, ldc;   // Kc = per-z chunk (== K when unsplit)
  const float* bias; const float* pos;
  float* fout; u16* bout;
  u16 *qp, *kp, *vtp;                // for M_FC2: qp=partial0, kp=partial1
};

template<int MODE, int BN>
__global__ __launch_bounds__(256)
void gemm_bt(GA g) {
  constexpr int NI = BN / 32;                  // B fragments per wave
  __shared__ __align__(16) u16 As[3][128 * 32];
  __shared__ __align__(16) u16 Bs[3][BN * 32];
  const int tid = threadIdx.x;
  const u16* A  = g.A  + (long)blockIdx.z * g.Kc;
  const u16* Bt = g.Bt + (long)blockIdx.z * g.Kc;

  // bijective XCD swizzle (m204): consecutive local ids share the A-panel
  int tM, tN;
  {
    const int nwg = gridDim.x * gridDim.y;
    int flat = blockIdx.y * gridDim.x + blockIdx.x;
    const int q = nwg >> 3, r = nwg & 7;
    const int xcd = flat & 7, loc = flat >> 3;
    flat = (xcd < r ? xcd * (q + 1) : r * (q + 1) + (xcd - r) * q) + loc;
    tM = flat / gridDim.x; tN = flat % gridDim.x;
  }

  const int lane = tid & 63, wid = tid >> 6;
  const int wr = wid >> 1, wc = wid & 1;       // 2x2 waves
  const int fr = lane & 15, fg = lane >> 4;

  const int arow = tM * 128 + (tid >> 2);
  int br0 = tN * BN + (tid >> 2);
  if (br0 > g.Nrows - 1) br0 = g.Nrows - 1;
  int br1 = tN * BN + 64 + (tid >> 2);
  if (br1 > g.Nrows - 1) br1 = g.Nrows - 1;
  // pre-swizzled SOURCE chunk (both-sides swizzle, rule #21)
  const int kseg = ((tid & 3) ^ ((tid >> 3) & 3)) * 8;
  const int woff = (tid & 192) * 8;            // wave-uniform LDS offset (elems)

  const u16* ag0 = A  + (long)arow        * g.lda + kseg;
  const u16* ag1 = A  + (long)(arow + 64) * g.lda + kseg;
  const u16* bg0 = Bt + (long)br0         * g.ldb + kseg;
  const u16* bg1 = Bt + (long)br1         * g.ldb + kseg;

  f32x4 acc[4][NI];
#pragma unroll
  for (int i = 0; i < 4; ++i)
#pragma unroll
    for (int j = 0; j < NI; ++j) acc[i][j] = f32x4{0.f, 0.f, 0.f, 0.f};

#define STAGE(KT, BUF) do {                                   \
    const int _k0 = (KT) << 5;                                \
    gll16(ag0 + _k0, &As[BUF][woff]);                         \
    gll16(ag1 + _k0, &As[BUF][woff + 2048]);                  \
    gll16(bg0 + _k0, &Bs[BUF][woff]);                         \
    if (BN == 128) gll16(bg1 + _k0, &Bs[BUF][woff + 2048]);   \
  } while (0)

  const int nk = g.Kc >> 5;
  STAGE(0, 0);
  if (nk > 1) STAGE(1, 1);

  // read-side swizzle: physical chunk for logical fg of row (..+fr)
  const int rsw = (fg ^ ((fr >> 1) & 3)) * 8;
  constexpr int LPS = (BN == 128) ? 4 : 3;     // loads per stage

  for (int kt = 0; kt < nk; ++kt) {
    const int cur = kt % 3;
    if (kt < nk - 1) {
      asm volatile("s_waitcnt vmcnt(%0)" :: "i"(LPS) : "memory");
    } else {
      asm volatile("s_waitcnt vmcnt(0)" ::: "memory");
    }
    __builtin_amdgcn_sched_barrier(0);
    __builtin_amdgcn_s_barrier();
    __builtin_amdgcn_sched_barrier(0);
    if (kt + 2 < nk) STAGE(kt + 2, (kt + 2) % 3);

    bf16x8 af[4], bfr[NI];
#pragma unroll
    for (int mi = 0; mi < 4; ++mi)
      af[mi] = *(const bf16x8*)&As[cur][(wr * 64 + mi * 16 + fr) * 32 + rsw];
#pragma unroll
    for (int ni = 0; ni < NI; ++ni)
      bfr[ni] = *(const bf16x8*)&Bs[cur][(wc * (BN / 2) + ni * 16 + fr) * 32 + rsw];
    __builtin_amdgcn_s_setprio(1);
#pragma unroll
    for (int mi = 0; mi < 4; ++mi)
#pragma unroll
      for (int ni = 0; ni < NI; ++ni)
        acc[mi][ni] = __builtin_amdgcn_mfma_f32_16x16x32_bf16(af[mi], bfr[ni], acc[mi][ni], 0, 0, 0);
    __builtin_amdgcn_s_setprio(0);
  }
#undef STAGE

#pragma unroll
  for (int mi = 0; mi < 4; ++mi)
#pragma unroll
    for (int ni = 0; ni < NI; ++ni)
#pragma unroll
      for (int j = 0; j < 4; ++j) {
        const int row = tM * 128 + wr * 64 + mi * 16 + fg * 4 + j;
        const int col = tN * BN + wc * (BN / 2) + ni * 16 + fr;
        float v = acc[mi][ni][j];
        if (MODE == M_EMBED) {
          const int b = row >> 9, t = row & 511;
          v += g.bias[col] + g.pos[(long)t * E + col];
          g.fout[((long)(b * S + t)) * E + col] = v;
        } else if (MODE == M_QKV) {
          const int b = row / S, s = row - b * S;
          v += g.bias[col];
          const int part = col >> 10, c = col & 1023;
          const int hh = c >> 6, d = c & 63;
          const u16 bf = f2bf(v);
          if (part == 0)      g.qp [((long)((b * NHd + hh) * SPAD + s)) * HD + d] = bf;
          else if (part == 1) g.kp [((long)((b * NHd + hh) * SPAD + s)) * HD + d] = bf;
          else                g.vtp[((long)((b * NHd + hh) * HD   + d)) * SPAD + s] = bf;
        } else if (MODE == M_OPROJ) {
          const long idx = (long)row * g.ldc + col;
          g.fout[idx] += v + g.bias[col];
        } else if (MODE == M_FC2) {
          // split-K: raw partial (no bias) -> bf16 streaming store
          u16* dst = blockIdx.z ? g.kp : g.qp;
          dst[(long)row * g.ldc + col] = f2bf(v);
        } else if (MODE == M_FC1) {
          v += g.bias[col];
          const float z = 0.7978845608028654f * (v + 0.044715f * v * v * v);
          const float e = __expf(2.f * z);
          const float th = 1.f - 2.f / (e + 1.f);   // tanh(z), overflow-safe
          g.bout[(long)row * g.ldc + col] = f2bf(0.5f * v * (1.f + th));
        } else if (MODE == M_HEAD) {
          g.fout[(long)row * g.ldc + col] = v + g.bias[col];
        }
      }
}

// ---------------- split-K reduce + residual + (optional) next-layer LN1 ------
template<int DOLN>
__global__ __launch_bounds__(256)
void red_ln(float* __restrict__ x, const u16* __restrict__ p0,
            const u16* __restrict__ p1, const float* __restrict__ bias,
            const float* __restrict__ sc, const float* __restrict__ bi,
            u16* __restrict__ out) {
  const int r = blockIdx.x;
  const int c4 = threadIdx.x;
  float4 v = ((const float4*)(x + (long)r * E))[c4];
  const ushort4 a = ((const ushort4*)(p0 + (long)r * E))[c4];
  const ushort4 b = ((const ushort4*)(p1 + (long)r * E))[c4];
  const float4 bb = ((const float4*)bias)[c4];
  v.x += bb.x + bf2f(a.x) + bf2f(b.x);
  v.y += bb.y + bf2f(a.y) + bf2f(b.y);
  v.z += bb.z + bf2f(a.z) + bf2f(b.z);
  v.w += bb.w + bf2f(a.w) + bf2f(b.w);
  ((float4*)(x + (long)r * E))[c4] = v;
  if (DOLN) {
    float s = v.x + v.y + v.z + v.w;
    float q = v.x * v.x + v.y * v.y + v.z * v.z + v.w * v.w;
#pragma unroll
    for (int o = 32; o; o >>= 1) { s += __shfl_down(s, o); q += __shfl_down(q, o); }
    __shared__ float ps[8];
    if ((threadIdx.x & 63) == 0) { ps[threadIdx.x >> 6] = s; ps[4 + (threadIdx.x >> 6)] = q; }
    __syncthreads();
    s = ps[0] + ps[1] + ps[2] + ps[3];
    q = ps[4] + ps[5] + ps[6] + ps[7];
    const float mean = s * (1.f / E);
    const float rs = rsqrtf(q * (1.f / E) - mean * mean + 1e-5f);
    const int c = threadIdx.x * 4;
    ushort4 o4;
    o4.x = f2bf((v.x - mean) * rs * sc[c + 0] + bi[c + 0]);
    o4.y = f2bf((v.y - mean) * rs * sc[c + 1] + bi[c + 1]);
    o4.z = f2bf((v.z - mean) * rs * sc[c + 2] + bi[c + 2]);
    o4.w = f2bf((v.w - mean) * rs * sc[c + 3] + bi[c + 3]);
    ((ushort4*)(out + (long)r * E))[threadIdx.x] = o4;
  }
}

// ---------------- fused flash attention, QBLK=128 (R10, verified) ----------------
__global__ __launch_bounds__(256)
void flash_k(const u16* __restrict__ q, const u16* __restrict__ k,
             const u16* __restrict__ vt, u16* __restrict__ o) {
  __shared__ __align__(16) u16 Ks[2][64 * 64];
  __shared__ __align__(16) u16 Vs[2][64 * 64];   // VT tile: [d][kv]
  __shared__ __align__(16) u16 Ps[4 * 32 * 64];
  const int tid = threadIdx.x;
  const int lane = tid & 63, w = tid >> 6;
  const int fr = lane & 15, fg = lane >> 4;

  // XCD swizzle: 1280 blocks % 8 == 0; contiguous bh chunks per XCD
  int flat = blockIdx.y * 5 + blockIdx.x;
  flat = (flat & 7) * 160 + (flat >> 3);
  const int bh = flat / 5, qt = flat % 5;
  const int q0 = qt * 128;

  bf16x8 qf[2][2];
#pragma unroll
  for (int ms = 0; ms < 2; ++ms) {
    int qr = q0 + w * 32 + ms * 16 + fr;
    if (qr > SPAD - 1) qr = SPAD - 1;
    const u16* qrow = q + ((long)bh * SPAD + qr) * HD;
    qf[ms][0] = *(const bf16x8*)(qrow + fg * 8);
    qf[ms][1] = *(const bf16x8*)(qrow + 32 + fg * 8);
  }

  const int srow = lane >> 3;
  const int sseg = (((lane & 7) ^ (srow & 7)) * 8);
  const u16* kg = k  + ((long)bh * SPAD + w * 16 + srow) * HD + sseg;
  const u16* vg = vt + ((long)(bh * HD + w * 16 + srow)) * SPAD + sseg;

#define STAGE_F(KT, BUF) do {                                       \
    gll16(kg + (KT) * 64 * HD,          &Ks[BUF][w * 16 * HD]);     \
    gll16(kg + (KT) * 64 * HD + 8 * HD, &Ks[BUF][w * 16 * HD + 8 * HD]); \
    gll16(vg + (KT) * 64,               &Vs[BUF][w * 16 * HD]);     \
    gll16(vg + (KT) * 64 + 8 * SPAD,    &Vs[BUF][w * 16 * HD + 8 * HD]); \
  } while (0)

  const int frm = fr & 7;

  float m[2][4], lsum[2][4]; f32x4 oa[2][4];
#pragma unroll
  for (int ms = 0; ms < 2; ++ms)
#pragma unroll
    for (int j = 0; j < 4; ++j) { m[ms][j] = -1e30f; lsum[ms][j] = 0.f; }
#pragma unroll
  for (int ms = 0; ms < 2; ++ms)
#pragma unroll
    for (int n = 0; n < 4; ++n) oa[ms][n] = f32x4{0.f, 0.f, 0.f, 0.f};

  const int nt = (qt < 4) ? 8 : 9;
  STAGE_F(0, 0);
  for (int kt = 0; kt < nt; ++kt) {
    const int cur = kt & 1;
    asm volatile("s_waitcnt vmcnt(0)" ::: "memory");
    __builtin_amdgcn_sched_barrier(0);
    __builtin_amdgcn_s_barrier();
    __builtin_amdgcn_sched_barrier(0);
    if (kt + 1 < nt) STAGE_F(kt + 1, cur ^ 1);

    f32x4 sfr[2][4];
#pragma unroll
    for (int n = 0; n < 4; ++n) {
      const bf16x8 kf0 = *(const bf16x8*)&Ks[cur][(n * 16 + fr) * HD + ((fg ^ frm) * 8)];
      const bf16x8 kf1 = *(const bf16x8*)&Ks[cur][(n * 16 + fr) * HD + (((fg + 4) ^ frm) * 8)];
#pragma unroll
      for (int ms = 0; ms < 2; ++ms) {
        sfr[ms][n] = __builtin_amdgcn_mfma_f32_16x16x32_bf16(qf[ms][0], kf0, f32x4{0.f,0.f,0.f,0.f}, 0, 0, 0);
        sfr[ms][n] = __builtin_amdgcn_mfma_f32_16x16x32_bf16(qf[ms][1], kf1, sfr[ms][n], 0, 0, 0);
      }
    }
    float p[2][4][4];
#pragma unroll
    for (int ms = 0; ms < 2; ++ms)
#pragma unroll
      for (int j = 0; j < 4; ++j) {
        const int qg = q0 + w * 32 + ms * 16 + fg * 4 + j;
        const int vlim = qg < Tt ? Tt : qg + 1;
#pragma unroll
        for (int n = 0; n < 4; ++n) {
          const int col = kt * 64 + n * 16 + fr;
          p[ms][n][j] = (col < vlim) ? sfr[ms][n][j] * 0.125f : -1e30f;
        }
      }
#pragma unroll
    for (int ms = 0; ms < 2; ++ms)
#pragma unroll
      for (int j = 0; j < 4; ++j) {
        float pm = fmaxf(fmaxf(p[ms][0][j], p[ms][1][j]), fmaxf(p[ms][2][j], p[ms][3][j]));
#pragma unroll
        for (int msk = 1; msk <= 8; msk <<= 1) pm = fmaxf(pm, __shfl_xor(pm, msk));
        const float mn = fmaxf(m[ms][j], pm);
        const float corr = __expf(m[ms][j] - mn);
        m[ms][j] = mn;
        float rs = 0.f;
#pragma unroll
        for (int n = 0; n < 4; ++n) { const float e = __expf(p[ms][n][j] - mn); p[ms][n][j] = e; rs += e; }
#pragma unroll
        for (int msk = 1; msk <= 8; msk <<= 1) rs += __shfl_xor(rs, msk);
        lsum[ms][j] = lsum[ms][j] * corr + rs;
#pragma unroll
        for (int n = 0; n < 4; ++n) oa[ms][n][j] *= corr;
      }
#pragma unroll
    for (int ms = 0; ms < 2; ++ms)
#pragma unroll
      for (int j = 0; j < 4; ++j) {
        const int r = ms * 16 + fg * 4 + j;
#pragma unroll
        for (int n = 0; n < 4; ++n) {
          const int gr = 2 * n + (fr >> 3);
          Ps[w * 2048 + r * 64 + ((gr ^ (r & 7)) * 8) + frm] = f2bf(p[ms][n][j]);
        }
      }
    asm volatile("s_waitcnt lgkmcnt(0)" ::: "memory");
    __builtin_amdgcn_sched_barrier(0);
    bf16x8 pf[2][2];
#pragma unroll
    for (int ms = 0; ms < 2; ++ms) {
      pf[ms][0] = *(const bf16x8*)&Ps[w * 2048 + (ms * 16 + fr) * 64 + ((fg ^ frm) * 8)];
      pf[ms][1] = *(const bf16x8*)&Ps[w * 2048 + (ms * 16 + fr) * 64 + (((fg + 4) ^ frm) * 8)];
    }
#pragma unroll
    for (int n = 0; n < 4; ++n) {
      const bf16x8 vf0 = *(const bf16x8*)&Vs[cur][(n * 16 + fr) * HD + ((fg ^ frm) * 8)];
      const bf16x8 vf1 = *(const bf16x8*)&Vs[cur][(n * 16 + fr) * HD + (((fg + 4) ^ frm) * 8)];
#pragma unroll
      for (int ms = 0; ms < 2; ++ms) {
        oa[ms][n] = __builtin_amdgcn_mfma_f32_16x16x32_bf16(pf[ms][0], vf0, oa[ms][n], 0, 0, 0);
        oa[ms][n] = __builtin_amdgcn_mfma_f32_16x16x32_bf16(pf[ms][1], vf1, oa[ms][n], 0, 0, 0);
      }
    }
  }
#undef STAGE_F

  const int b = bh >> 4, hh = bh & 15;
#pragma unroll
  for (int ms = 0; ms < 2; ++ms)
#pragma unroll
    for (int j = 0; j < 4; ++j) {
      const int qg = q0 + w * 32 + ms * 16 + fg * 4 + j;
      if (qg < S) {
        const float inv = 1.f / lsum[ms][j];
#pragma unroll
        for (int n = 0; n < 4; ++n)
          o[((long)(b * S + qg)) * E + hh * HD + n * 16 + fr] = f2bf(oa[ms][n][j] * inv);
      }
    }
}

// ---------------- LayerNorm ----------------
__global__ __launch_bounds__(256)
void ln_k(const float* __restrict__ x, const float* __restrict__ sc,
          const float* __restrict__ bi, u16* __restrict__ out, int gather) {
  const int r = blockIdx.x;
  const int srow = gather ? ((r >> 4) * S + Tt + (r & 15)) : r;
  const float4 v = ((const float4*)(x + (long)srow * E))[threadIdx.x];
  float s = v.x + v.y + v.z + v.w;
  float q = v.x * v.x + v.y * v.y + v.z * v.z + v.w * v.w;
#pragma unroll
  for (int o = 32; o; o >>= 1) { s += __shfl_down(s, o); q += __shfl_down(q, o); }
  __shared__ float ps[8];
  if ((threadIdx.x & 63) == 0) { ps[threadIdx.x >> 6] = s; ps[4 + (threadIdx.x >> 6)] = q; }
  __syncthreads();
  s = ps[0] + ps[1] + ps[2] + ps[3];
  q = ps[4] + ps[5] + ps[6] + ps[7];
  const float mean = s * (1.f / E);
  const float rs = rsqrtf(q * (1.f / E) - mean * mean + 1e-5f);
  const int c = threadIdx.x * 4;
  ushort4 o4;
  o4.x = f2bf((v.x - mean) * rs * sc[c + 0] + bi[c + 0]);
  o4.y = f2bf((v.y - mean) * rs * sc[c + 1] + bi[c + 1]);
  o4.z = f2bf((v.z - mean) * rs * sc[c + 2] + bi[c + 2]);
  o4.w = f2bf((v.w - mean) * rs * sc[c + 3] + bi[c + 3]);
  ((ushort4*)(out + (long)r * E))[threadIdx.x] = o4;
}

// ---------------- transpose f32[R,C] -> bf16[C,R] ----------------
__global__ __launch_bounds__(256)
void wtrans(const float* __restrict__ src, u16* __restrict__ dst, int R, int C) {
  __shared__ float t[32][33];
  const int c0 = blockIdx.x * 32, r0 = blockIdx.y * 32;
  const int tx = threadIdx.x & 31, ty = threadIdx.x >> 5;
#pragma unroll
  for (int i = 0; i < 32; i += 8) t[ty + i][tx] = src[(long)(r0 + ty + i) * C + c0 + tx];
  __syncthreads();
#pragma unroll
  for (int i = 0; i < 32; i += 8) dst[(long)(c0 + ty + i) * R + r0 + tx] = f2bf(t[tx][ty + i]);
}

// ---------------- merged per-layer weight transpose (4 weights, 1 launch) ----
struct WT4 {
  const float* s[4]; u16* d[4];
  int R[4], C[4], tx[4], st[4];
};
__global__ __launch_bounds__(256)
void wtrans4(WT4 a) {
  const int bid = blockIdx.x;
  const int wsel = (bid >= a.st[1]) + (bid >= a.st[2]) + (bid >= a.st[3]);
  const int t = bid - a.st[wsel];
  const int c0 = (t % a.tx[wsel]) * 32, r0 = (t / a.tx[wsel]) * 32;
  const float* src = a.s[wsel]; u16* dst = a.d[wsel];
  const int R = a.R[wsel], C = a.C[wsel];
  __shared__ float tt[32][33];
  const int tx = threadIdx.x & 31, ty = threadIdx.x >> 5;
#pragma unroll
  for (int i = 0; i < 32; i += 8) tt[ty + i][tx] = src[(long)(r0 + ty + i) * C + c0 + tx];
  __syncthreads();
#pragma unroll
  for (int i = 0; i < 32; i += 8) dst[(long)(c0 + ty + i) * R + r0 + tx] = f2bf(tt[tx][ty + i]);
}

// ---------------- small utility kernels ----------------
__global__ void cvt_bf(const float* __restrict__ in, u16* __restrict__ out, long n) {
  const long i = ((long)blockIdx.x * blockDim.x + threadIdx.x) * 4;
  if (i >= n) return;
  const float4 v = *(const float4*)(in + i);
  ushort4 o; o.x = f2bf(v.x); o.y = f2bf(v.y); o.z = f2bf(v.z); o.w = f2bf(v.w);
  *(ushort4*)(out + i) = o;
}

__global__ void zero_k(float4* p, long n) {
  long i = (long)blockIdx.x * blockDim.x + threadIdx.x;
  const long st = (long)gridDim.x * blockDim.x;
  const float4 z = make_float4(0.f, 0.f, 0.f, 0.f);
  for (; i < n; i += st) p[i] = z;
}

__global__ void reg_copy(const float* __restrict__ regs, float* __restrict__ x) {
  const int b = blockIdx.x >> 4, r = blockIdx.x & 15;
  const float4* sp = (const float4*)(regs + (long)r * E);
  float4* dp = (float4*)(x + ((long)(b * S + Tt + r)) * E);
  dp[threadIdx.x] = sp[threadIdx.x];
}

// ---------------- workspace layout (bytes, all 16-aligned) ----------------
constexpr long OFF_WQKV = 0L;                                // per-layer, reused
constexpr long OFF_WO   = OFF_WQKV + 3072L * 1024 * 2;
constexpr long OFF_WFC1 = OFF_WO   + 1024L * 1024 * 2;
constexpr long OFF_WFC2 = OFF_WFC1 + 4096L * 1024 * 2;
constexpr long OFF_WEMB = OFF_WFC2 + 1024L * 4096 * 2;
constexpr long OFF_WHEAD= OFF_WEMB + 1024L * 64 * 2;
constexpr long OFF_SMP  = OFF_WHEAD+ 256L * 1024 * 2;
constexpr long OFF_X    = OFF_SMP  + (long)ME * 64 * 2;
constexpr long OFF_H    = OFF_X    + (long)MR * E * 4;
constexpr long OFF_Q    = OFF_H    + (long)MR * E * 2;
constexpr long OFF_K    = OFF_Q    + 256L * SPAD * HD * 2;   // also fc2 partial0
constexpr long OFF_VT   = OFF_K    + 256L * SPAD * HD * 2;   // also fc2 partial1
constexpr long OFF_O    = OFF_VT   + 256L * SPAD * HD * 2;   // a1 overlays o
constexpr long OFF_HF   = OFF_O    + (long)MR * FF * 2;
constexpr long WS_NEED  = OFF_HF   + 256L * 1024 * 2;        // ~196 MB

extern "C" void kernel_launch(void* const* d_in, const int* in_sizes, int n_in,
                              void* d_out, int out_size, void* d_ws, size_t ws_size,
                              hipStream_t stream) {
  if (ws_size < (size_t)WS_NEED) return;

  const float* sample = (const float*)d_in[0];
  const float* W_emb  = (const float*)d_in[1];
  const float* b_emb  = (const float*)d_in[2];
  const float* pos    = (const float*)d_in[3];
  const float* regs   = (const float*)d_in[4];
  const float* ln1_s  = (const float*)d_in[5];
  const float* ln1_b  = (const float*)d_in[6];
  const float* W_qkv  = (const float*)d_in[7];
  const float* b_qkv  = (const float*)d_in[8];
  const float* W_o    = (const float*)d_in[9];
  const float* b_o    = (const float*)d_in[10];
  const float* ln2_s  = (const float*)d_in[11];
  const float* ln2_b  = (const float*)d_in[12];
  const float* W_fc1  = (const float*)d_in[13];
  const float* b_fc1  = (const float*)d_in[14];
  const float* W_fc2  = (const float*)d_in[15];
  const float* b_fc2  = (const float*)d_in[16];
  const float* lnf_s  = (const float*)d_in[17];
  const float* lnf_b  = (const float*)d_in[18];
  const float* W_head = (const float*)d_in[19];
  const float* b_head = (const float*)d_in[20];

  char* w = (char*)d_ws;
  u16* wqkvT = (u16*)(w + OFF_WQKV);
  u16* woT   = (u16*)(w + OFF_WO);
  u16* wfc1T = (u16*)(w + OFF_WFC1);
  u16* wfc2T = (u16*)(w + OFF_WFC2);
  u16* wembT = (u16*)(w + OFF_WEMB);
  u16* wheadT= (u16*)(w + OFF_WHEAD);
  u16* smp   = (u16*)(w + OFF_SMP);
  float* x   = (float*)(w + OFF_X);
  u16* h     = (u16*)(w + OFF_H);
  u16* qp    = (u16*)(w + OFF_Q);
  u16* kp    = (u16*)(w + OFF_K);
  u16* vtp   = (u16*)(w + OFF_VT);
  u16* o     = (u16*)(w + OFF_O);
  u16* a1    = (u16*)(w + OFF_O);   // overlay: o dead when a1 live
  u16* hf    = (u16*)(w + OFF_HF);

  // ---- one-time prep ----
  wtrans<<<dim3(32, 2, 1), 256, 0, stream>>>(W_emb,  wembT, 64, 1024);
  wtrans<<<dim3(8, 32, 1), 256, 0, stream>>>(W_head, wheadT, 1024, 256);
  cvt_bf<<<dim3(512), 256, 0, stream>>>(sample, smp, (long)ME * 64);
  zero_k<<<dim3(2048), 256, 0, stream>>>((float4*)qp, (3L * 256 * SPAD * HD * 2) / 16);

  // ---- embed + registers ----
  {
    GA g{}; g.A = smp; g.Bt = wembT; g.K = 64; g.Kc = 64; g.lda = 64; g.ldb = 64;
    g.Nrows = E; g.bias = b_emb; g.pos = pos; g.fout = x;
    gemm_bt<M_EMBED, 64><<<dim3(16, 64, 1), 256, 0, stream>>>(g);
  }
  reg_copy<<<dim3(256), 256, 0, stream>>>(regs, x);

  for (int L = 0; L < DEPTH; ++L) {
    // merged per-layer weight transpose (1 launch for qkv/o/fc1/fc2)
    {
      WT4 a;
      a.s[0] = W_qkv + (long)L * 1024 * 3072; a.d[0] = wqkvT; a.R[0] = 1024; a.C[0] = 3072; a.tx[0] = 96;  a.st[0] = 0;
      a.s[1] = W_o   + (long)L * 1024 * 1024; a.d[1] = woT;   a.R[1] = 1024; a.C[1] = 1024; a.tx[1] = 32;  a.st[1] = 3072;
      a.s[2] = W_fc1 + (long)L * 1024 * 4096; a.d[2] = wfc1T; a.R[2] = 1024; a.C[2] = 4096; a.tx[2] = 128; a.st[2] = 4096;
      a.s[3] = W_fc2 + (long)L * 4096 * 1024; a.d[3] = wfc2T; a.R[3] = 4096; a.C[3] = 1024; a.tx[3] = 32;  a.st[3] = 8192;
      wtrans4<<<dim3(12288), 256, 0, stream>>>(a);
    }

    // ln1: layer 0 standalone; layers 1..7 were fused into red_ln of L-1
    if (L == 0)
      ln_k<<<dim3(MR), 256, 0, stream>>>(x, ln1_s, ln1_b, h, 0);
    {
      GA g{}; g.A = h; g.Bt = wqkvT;
      g.K = 1024; g.Kc = 1024; g.lda = 1024; g.ldb = 1024; g.Nrows = 3072;
      g.bias = b_qkv + L * 3072; g.qp = qp; g.kp = kp; g.vtp = vtp;
      gemm_bt<M_QKV, 128><<<dim3(24, 66, 1), 256, 0, stream>>>(g);
    }
    flash_k<<<dim3(5, 256, 1), 256, 0, stream>>>(qp, kp, vtp, o);
    {
      GA g{}; g.A = o; g.Bt = woT;
      g.K = 1024; g.Kc = 1024; g.lda = 1024; g.ldb = 1024; g.Nrows = 1024; g.ldc = 1024;
      g.bias = b_o + L * E; g.fout = x;
      gemm_bt<M_OPROJ, 128><<<dim3(8, 66, 1), 256, 0, stream>>>(g);
    }
    ln_k<<<dim3(MR), 256, 0, stream>>>(x, ln2_s + L * E, ln2_b + L * E, h, 0);
    {
      GA g{}; g.A = h; g.Bt = wfc1T;
      g.K = 1024; g.Kc = 1024; g.lda = 1024; g.ldb = 1024; g.Nrows = 4096; g.ldc = 4096;
      g.bias = b_fc1 + L * FF; g.bout = a1;
      gemm_bt<M_FC1, 128><<<dim3(32, 66, 1), 256, 0, stream>>>(g);
    }
    {
      // fc2 split-K x2: bf16 partials into kp (z=0) / vtp (z=1); kp/vtp are
      // dead here and fully safe to scribble (pads: K masked, V x P=0).
      GA g{}; g.A = a1; g.Bt = wfc2T;
      g.K = 4096; g.Kc = 2048; g.lda = 4096; g.ldb = 4096; g.Nrows = 1024; g.ldc = 1024;
      g.qp = kp; g.kp = vtp;
      gemm_bt<M_FC2, 128><<<dim3(8, 66, 2), 256, 0, stream>>>(g);
    }
    // reduce partials + bias + residual; fuse next layer's ln1 when L<7
    if (L < DEPTH - 1)
      red_ln<1><<<dim3(MR), 256, 0, stream>>>(x, kp, vtp, b_fc2 + L * E,
                                              ln1_s + (L + 1) * E, ln1_b + (L + 1) * E, h);
    else
      red_ln<0><<<dim3(MR), 256, 0, stream>>>(x, kp, vtp, b_fc2 + L * E,
                                              lnf_s, lnf_b, h);
  }

  ln_k<<<dim3(256), 256, 0, stream>>>(x, lnf_s, lnf_b, hf, 1);
  {
    GA g{}; g.A = hf; g.Bt = wheadT; g.K = 1024; g.Kc = 1024; g.lda = 1024; g.ldb = 1024;
    g.Nrows = LAT; g.ldc = LAT; g.bias = b_head; g.fout = (float*)d_out;
    gemm_bt<M_HEAD, 64><<<dim3(4, 2, 1), 256, 0, stream>>>(g);
  }
}

// Round 17
// 3789.288 us; speedup vs baseline: 1.3418x; 1.0113x over previous
//
#include <hip/hip_runtime.h>
#include <hip/hip_bf16.h>

// RegisterEncoder: 8-layer pre-LN transformer, bf16 MFMA GEMMs, f32 residual.
// Round 17: replicate R16's proven split-K+fused-LN mechanism on oproj:
// oproj -> split-K x2 (1056 blocks, Kc=512), bf16 partials into dead kp/vtp,
// red_ln<1> fuses residual+bias+ln2 (removes 8 ln_k launches). fc2 reuses
// kp/vtp after (dead again). Everything else identical to R16 (3832us).

typedef unsigned short u16;
typedef __attribute__((ext_vector_type(4))) float f32x4;
typedef __attribute__((ext_vector_type(8))) __bf16 bf16x8;

#define DEV static __device__ __forceinline__

constexpr int Bb = 16, Tt = 512, E = 1024, HD = 64, NHd = 16;
constexpr int DEPTH = 8, NREG = 16, LAT = 256, FF = 4096;
constexpr int S = Tt + NREG;   // 528
constexpr int SPAD = 576;      // padded attention seq (9 x 64)
constexpr int MR = Bb * S;     // 8448
constexpr int ME = Bb * Tt;    // 8192

DEV u16 f2bf(float f) {
  unsigned u = __builtin_bit_cast(unsigned, f);
  u += 0x7fffu + ((u >> 16) & 1u);
  return (u16)(u >> 16);
}
DEV float bf2f(u16 h) { return __builtin_bit_cast(float, (unsigned)h << 16); }

DEV void gll16(const u16* g, u16* l) {
  __builtin_amdgcn_global_load_lds((const __attribute__((address_space(1))) void*)g,
                                   (__attribute__((address_space(3))) void*)l, 16, 0, 0);
}

// ---------------- GEMM: C[M,N] = A[M,K](bf16) * Bt[N,K]^T(bf16) ----------------
enum { M_EMBED, M_QKV, M_OPROJ, M_FC1, M_FC2, M_HEAD };

struct GA {
  const u16* A; const u16* Bt;
  int K, Kc, lda, ldb, Nrows, ldc;   // Kc = per-z chunk (== K when unsplit)
  const float* bias; const float* pos;
  float* fout; u16* bout;
  u16 *qp, *kp, *vtp;                // for split modes: qp=partial0, kp=partial1
};

template<int MODE, int BN>
__global__ __launch_bounds__(256)
void gemm_bt(GA g) {
  constexpr int NI = BN / 32;                  // B fragments per wave
  __shared__ __align__(16) u16 As[3][128 * 32];
  __shared__ __align__(16) u16 Bs[3][BN * 32];
  const int tid = threadIdx.x;
  const u16* A  = g.A  + (long)blockIdx.z * g.Kc;
  const u16* Bt = g.Bt + (long)blockIdx.z * g.Kc;

  // bijective XCD swizzle (m204): consecutive local ids share the A-panel
  int tM, tN;
  {
    const int nwg = gridDim.x * gridDim.y;
    int flat = blockIdx.y * gridDim.x + blockIdx.x;
    const int q = nwg >> 3, r = nwg & 7;
    const int xcd = flat & 7, loc = flat >> 3;
    flat = (xcd < r ? xcd * (q + 1) : r * (q + 1) + (xcd - r) * q) + loc;
    tM = flat / gridDim.x; tN = flat % gridDim.x;
  }

  const int lane = tid & 63, wid = tid >> 6;
  const int wr = wid >> 1, wc = wid & 1;       // 2x2 waves
  const int fr = lane & 15, fg = lane >> 4;

  const int arow = tM * 128 + (tid >> 2);
  int br0 = tN * BN + (tid >> 2);
  if (br0 > g.Nrows - 1) br0 = g.Nrows - 1;
  int br1 = tN * BN + 64 + (tid >> 2);
  if (br1 > g.Nrows - 1) br1 = g.Nrows - 1;
  // pre-swizzled SOURCE chunk (both-sides swizzle, rule #21)
  const int kseg = ((tid & 3) ^ ((tid >> 3) & 3)) * 8;
  const int woff = (tid & 192) * 8;            // wave-uniform LDS offset (elems)

  const u16* ag0 = A  + (long)arow        * g.lda + kseg;
  const u16* ag1 = A  + (long)(arow + 64) * g.lda + kseg;
  const u16* bg0 = Bt + (long)br0         * g.ldb + kseg;
  const u16* bg1 = Bt + (long)br1         * g.ldb + kseg;

  f32x4 acc[4][NI];
#pragma unroll
  for (int i = 0; i < 4; ++i)
#pragma unroll
    for (int j = 0; j < NI; ++j) acc[i][j] = f32x4{0.f, 0.f, 0.f, 0.f};

#define STAGE(KT, BUF) do {                                   \
    const int _k0 = (KT) << 5;                                \
    gll16(ag0 + _k0, &As[BUF][woff]);                         \
    gll16(ag1 + _k0, &As[BUF][woff + 2048]);                  \
    gll16(bg0 + _k0, &Bs[BUF][woff]);                         \
    if (BN == 128) gll16(bg1 + _k0, &Bs[BUF][woff + 2048]);   \
  } while (0)

  const int nk = g.Kc >> 5;
  STAGE(0, 0);
  if (nk > 1) STAGE(1, 1);

  // read-side swizzle: physical chunk for logical fg of row (..+fr)
  const int rsw = (fg ^ ((fr >> 1) & 3)) * 8;
  constexpr int LPS = (BN == 128) ? 4 : 3;     // loads per stage

  for (int kt = 0; kt < nk; ++kt) {
    const int cur = kt % 3;
    if (kt < nk - 1) {
      asm volatile("s_waitcnt vmcnt(%0)" :: "i"(LPS) : "memory");
    } else {
      asm volatile("s_waitcnt vmcnt(0)" ::: "memory");
    }
    __builtin_amdgcn_sched_barrier(0);
    __builtin_amdgcn_s_barrier();
    __builtin_amdgcn_sched_barrier(0);
    if (kt + 2 < nk) STAGE(kt + 2, (kt + 2) % 3);

    bf16x8 af[4], bfr[NI];
#pragma unroll
    for (int mi = 0; mi < 4; ++mi)
      af[mi] = *(const bf16x8*)&As[cur][(wr * 64 + mi * 16 + fr) * 32 + rsw];
#pragma unroll
    for (int ni = 0; ni < NI; ++ni)
      bfr[ni] = *(const bf16x8*)&Bs[cur][(wc * (BN / 2) + ni * 16 + fr) * 32 + rsw];
    __builtin_amdgcn_s_setprio(1);
#pragma unroll
    for (int mi = 0; mi < 4; ++mi)
#pragma unroll
      for (int ni = 0; ni < NI; ++ni)
        acc[mi][ni] = __builtin_amdgcn_mfma_f32_16x16x32_bf16(af[mi], bfr[ni], acc[mi][ni], 0, 0, 0);
    __builtin_amdgcn_s_setprio(0);
  }
#undef STAGE

#pragma unroll
  for (int mi = 0; mi < 4; ++mi)
#pragma unroll
    for (int ni = 0; ni < NI; ++ni)
#pragma unroll
      for (int j = 0; j < 4; ++j) {
        const int row = tM * 128 + wr * 64 + mi * 16 + fg * 4 + j;
        const int col = tN * BN + wc * (BN / 2) + ni * 16 + fr;
        float v = acc[mi][ni][j];
        if (MODE == M_EMBED) {
          const int b = row >> 9, t = row & 511;
          v += g.bias[col] + g.pos[(long)t * E + col];
          g.fout[((long)(b * S + t)) * E + col] = v;
        } else if (MODE == M_QKV) {
          const int b = row / S, s = row - b * S;
          v += g.bias[col];
          const int part = col >> 10, c = col & 1023;
          const int hh = c >> 6, d = c & 63;
          const u16 bf = f2bf(v);
          if (part == 0)      g.qp [((long)((b * NHd + hh) * SPAD + s)) * HD + d] = bf;
          else if (part == 1) g.kp [((long)((b * NHd + hh) * SPAD + s)) * HD + d] = bf;
          else                g.vtp[((long)((b * NHd + hh) * HD   + d)) * SPAD + s] = bf;
        } else if (MODE == M_OPROJ || MODE == M_FC2) {
          // split-K: raw partial (no bias) -> bf16 streaming store
          u16* dst = blockIdx.z ? g.kp : g.qp;
          dst[(long)row * g.ldc + col] = f2bf(v);
        } else if (MODE == M_FC1) {
          v += g.bias[col];
          const float z = 0.7978845608028654f * (v + 0.044715f * v * v * v);
          const float e = __expf(2.f * z);
          const float th = 1.f - 2.f / (e + 1.f);   // tanh(z), overflow-safe
          g.bout[(long)row * g.ldc + col] = f2bf(0.5f * v * (1.f + th));
        } else if (MODE == M_HEAD) {
          g.fout[(long)row * g.ldc + col] = v + g.bias[col];
        }
      }
}

// ---------------- split-K reduce + residual + (optional) fused LN ------------
template<int DOLN>
__global__ __launch_bounds__(256)
void red_ln(float* __restrict__ x, const u16* __restrict__ p0,
            const u16* __restrict__ p1, const float* __restrict__ bias,
            const float* __restrict__ sc, const float* __restrict__ bi,
            u16* __restrict__ out) {
  const int r = blockIdx.x;
  const int c4 = threadIdx.x;
  float4 v = ((const float4*)(x + (long)r * E))[c4];
  const ushort4 a = ((const ushort4*)(p0 + (long)r * E))[c4];
  const ushort4 b = ((const ushort4*)(p1 + (long)r * E))[c4];
  const float4 bb = ((const float4*)bias)[c4];
  v.x += bb.x + bf2f(a.x) + bf2f(b.x);
  v.y += bb.y + bf2f(a.y) + bf2f(b.y);
  v.z += bb.z + bf2f(a.z) + bf2f(b.z);
  v.w += bb.w + bf2f(a.w) + bf2f(b.w);
  ((float4*)(x + (long)r * E))[c4] = v;
  if (DOLN) {
    float s = v.x + v.y + v.z + v.w;
    float q = v.x * v.x + v.y * v.y + v.z * v.z + v.w * v.w;
#pragma unroll
    for (int o = 32; o; o >>= 1) { s += __shfl_down(s, o); q += __shfl_down(q, o); }
    __shared__ float ps[8];
    if ((threadIdx.x & 63) == 0) { ps[threadIdx.x >> 6] = s; ps[4 + (threadIdx.x >> 6)] = q; }
    __syncthreads();
    s = ps[0] + ps[1] + ps[2] + ps[3];
    q = ps[4] + ps[5] + ps[6] + ps[7];
    const float mean = s * (1.f / E);
    const float rs = rsqrtf(q * (1.f / E) - mean * mean + 1e-5f);
    const int c = threadIdx.x * 4;
    ushort4 o4;
    o4.x = f2bf((v.x - mean) * rs * sc[c + 0] + bi[c + 0]);
    o4.y = f2bf((v.y - mean) * rs * sc[c + 1] + bi[c + 1]);
    o4.z = f2bf((v.z - mean) * rs * sc[c + 2] + bi[c + 2]);
    o4.w = f2bf((v.w - mean) * rs * sc[c + 3] + bi[c + 3]);
    ((ushort4*)(out + (long)r * E))[threadIdx.x] = o4;
  }
}

// ---------------- fused flash attention, QBLK=128 (R10, verified) ----------------
__global__ __launch_bounds__(256)
void flash_k(const u16* __restrict__ q, const u16* __restrict__ k,
             const u16* __restrict__ vt, u16* __restrict__ o) {
  __shared__ __align__(16) u16 Ks[2][64 * 64];
  __shared__ __align__(16) u16 Vs[2][64 * 64];   // VT tile: [d][kv]
  __shared__ __align__(16) u16 Ps[4 * 32 * 64];
  const int tid = threadIdx.x;
  const int lane = tid & 63, w = tid >> 6;
  const int fr = lane & 15, fg = lane >> 4;

  // XCD swizzle: 1280 blocks % 8 == 0; contiguous bh chunks per XCD
  int flat = blockIdx.y * 5 + blockIdx.x;
  flat = (flat & 7) * 160 + (flat >> 3);
  const int bh = flat / 5, qt = flat % 5;
  const int q0 = qt * 128;

  bf16x8 qf[2][2];
#pragma unroll
  for (int ms = 0; ms < 2; ++ms) {
    int qr = q0 + w * 32 + ms * 16 + fr;
    if (qr > SPAD - 1) qr = SPAD - 1;
    const u16* qrow = q + ((long)bh * SPAD + qr) * HD;
    qf[ms][0] = *(const bf16x8*)(qrow + fg * 8);
    qf[ms][1] = *(const bf16x8*)(qrow + 32 + fg * 8);
  }

  const int srow = lane >> 3;
  const int sseg = (((lane & 7) ^ (srow & 7)) * 8);
  const u16* kg = k  + ((long)bh * SPAD + w * 16 + srow) * HD + sseg;
  const u16* vg = vt + ((long)(bh * HD + w * 16 + srow)) * SPAD + sseg;

#define STAGE_F(KT, BUF) do {                                       \
    gll16(kg + (KT) * 64 * HD,          &Ks[BUF][w * 16 * HD]);     \
    gll16(kg + (KT) * 64 * HD + 8 * HD, &Ks[BUF][w * 16 * HD + 8 * HD]); \
    gll16(vg + (KT) * 64,               &Vs[BUF][w * 16 * HD]);     \
    gll16(vg + (KT) * 64 + 8 * SPAD,    &Vs[BUF][w * 16 * HD + 8 * HD]); \
  } while (0)

  const int frm = fr & 7;

  float m[2][4], lsum[2][4]; f32x4 oa[2][4];
#pragma unroll
  for (int ms = 0; ms < 2; ++ms)
#pragma unroll
    for (int j = 0; j < 4; ++j) { m[ms][j] = -1e30f; lsum[ms][j] = 0.f; }
#pragma unroll
  for (int ms = 0; ms < 2; ++ms)
#pragma unroll
    for (int n = 0; n < 4; ++n) oa[ms][n] = f32x4{0.f, 0.f, 0.f, 0.f};

  const int nt = (qt < 4) ? 8 : 9;
  STAGE_F(0, 0);
  for (int kt = 0; kt < nt; ++kt) {
    const int cur = kt & 1;
    asm volatile("s_waitcnt vmcnt(0)" ::: "memory");
    __builtin_amdgcn_sched_barrier(0);
    __builtin_amdgcn_s_barrier();
    __builtin_amdgcn_sched_barrier(0);
    if (kt + 1 < nt) STAGE_F(kt + 1, cur ^ 1);

    f32x4 sfr[2][4];
#pragma unroll
    for (int n = 0; n < 4; ++n) {
      const bf16x8 kf0 = *(const bf16x8*)&Ks[cur][(n * 16 + fr) * HD + ((fg ^ frm) * 8)];
      const bf16x8 kf1 = *(const bf16x8*)&Ks[cur][(n * 16 + fr) * HD + (((fg + 4) ^ frm) * 8)];
#pragma unroll
      for (int ms = 0; ms < 2; ++ms) {
        sfr[ms][n] = __builtin_amdgcn_mfma_f32_16x16x32_bf16(qf[ms][0], kf0, f32x4{0.f,0.f,0.f,0.f}, 0, 0, 0);
        sfr[ms][n] = __builtin_amdgcn_mfma_f32_16x16x32_bf16(qf[ms][1], kf1, sfr[ms][n], 0, 0, 0);
      }
    }
    float p[2][4][4];
#pragma unroll
    for (int ms = 0; ms < 2; ++ms)
#pragma unroll
      for (int j = 0; j < 4; ++j) {
        const int qg = q0 + w * 32 + ms * 16 + fg * 4 + j;
        const int vlim = qg < Tt ? Tt : qg + 1;
#pragma unroll
        for (int n = 0; n < 4; ++n) {
          const int col = kt * 64 + n * 16 + fr;
          p[ms][n][j] = (col < vlim) ? sfr[ms][n][j] * 0.125f : -1e30f;
        }
      }
#pragma unroll
    for (int ms = 0; ms < 2; ++ms)
#pragma unroll
      for (int j = 0; j < 4; ++j) {
        float pm = fmaxf(fmaxf(p[ms][0][j], p[ms][1][j]), fmaxf(p[ms][2][j], p[ms][3][j]));
#pragma unroll
        for (int msk = 1; msk <= 8; msk <<= 1) pm = fmaxf(pm, __shfl_xor(pm, msk));
        const float mn = fmaxf(m[ms][j], pm);
        const float corr = __expf(m[ms][j] - mn);
        m[ms][j] = mn;
        float rs = 0.f;
#pragma unroll
        for (int n = 0; n < 4; ++n) { const float e = __expf(p[ms][n][j] - mn); p[ms][n][j] = e; rs += e; }
#pragma unroll
        for (int msk = 1; msk <= 8; msk <<= 1) rs += __shfl_xor(rs, msk);
        lsum[ms][j] = lsum[ms][j] * corr + rs;
#pragma unroll
        for (int n = 0; n < 4; ++n) oa[ms][n][j] *= corr;
      }
#pragma unroll
    for (int ms = 0; ms < 2; ++ms)
#pragma unroll
      for (int j = 0; j < 4; ++j) {
        const int r = ms * 16 + fg * 4 + j;
#pragma unroll
        for (int n = 0; n < 4; ++n) {
          const int gr = 2 * n + (fr >> 3);
          Ps[w * 2048 + r * 64 + ((gr ^ (r & 7)) * 8) + frm] = f2bf(p[ms][n][j]);
        }
      }
    asm volatile("s_waitcnt lgkmcnt(0)" ::: "memory");
    __builtin_amdgcn_sched_barrier(0);
    bf16x8 pf[2][2];
#pragma unroll
    for (int ms = 0; ms < 2; ++ms) {
      pf[ms][0] = *(const bf16x8*)&Ps[w * 2048 + (ms * 16 + fr) * 64 + ((fg ^ frm) * 8)];
      pf[ms][1] = *(const bf16x8*)&Ps[w * 2048 + (ms * 16 + fr) * 64 + (((fg + 4) ^ frm) * 8)];
    }
#pragma unroll
    for (int n = 0; n < 4; ++n) {
      const bf16x8 vf0 = *(const bf16x8*)&Vs[cur][(n * 16 + fr) * HD + ((fg ^ frm) * 8)];
      const bf16x8 vf1 = *(const bf16x8*)&Vs[cur][(n * 16 + fr) * HD + (((fg + 4) ^ frm) * 8)];
#pragma unroll
      for (int ms = 0; ms < 2; ++ms) {
        oa[ms][n] = __builtin_amdgcn_mfma_f32_16x16x32_bf16(pf[ms][0], vf0, oa[ms][n], 0, 0, 0);
        oa[ms][n] = __builtin_amdgcn_mfma_f32_16x16x32_bf16(pf[ms][1], vf1, oa[ms][n], 0, 0, 0);
      }
    }
  }
#undef STAGE_F

  const int b = bh >> 4, hh = bh & 15;
#pragma unroll
  for (int ms = 0; ms < 2; ++ms)
#pragma unroll
    for (int j = 0; j < 4; ++j) {
      const int qg = q0 + w * 32 + ms * 16 + fg * 4 + j;
      if (qg < S) {
        const float inv = 1.f / lsum[ms][j];
#pragma unroll
        for (int n = 0; n < 4; ++n)
          o[((long)(b * S + qg)) * E + hh * HD + n * 16 + fr] = f2bf(oa[ms][n][j] * inv);
      }
    }
}

// ---------------- LayerNorm ----------------
__global__ __launch_bounds__(256)
void ln_k(const float* __restrict__ x, const float* __restrict__ sc,
          const float* __restrict__ bi, u16* __restrict__ out, int gather) {
  const int r = blockIdx.x;
  const int srow = gather ? ((r >> 4) * S + Tt + (r & 15)) : r;
  const float4 v = ((const float4*)(x + (long)srow * E))[threadIdx.x];
  float s = v.x + v.y + v.z + v.w;
  float q = v.x * v.x + v.y * v.y + v.z * v.z + v.w * v.w;
#pragma unroll
  for (int o = 32; o; o >>= 1) { s += __shfl_down(s, o); q += __shfl_down(q, o); }
  __shared__ float ps[8];
  if ((threadIdx.x & 63) == 0) { ps[threadIdx.x >> 6] = s; ps[4 + (threadIdx.x >> 6)] = q; }
  __syncthreads();
  s = ps[0] + ps[1] + ps[2] + ps[3];
  q = ps[4] + ps[5] + ps[6] + ps[7];
  const float mean = s * (1.f / E);
  const float rs = rsqrtf(q * (1.f / E) - mean * mean + 1e-5f);
  const int c = threadIdx.x * 4;
  ushort4 o4;
  o4.x = f2bf((v.x - mean) * rs * sc[c + 0] + bi[c + 0]);
  o4.y = f2bf((v.y - mean) * rs * sc[c + 1] + bi[c + 1]);
  o4.z = f2bf((v.z - mean) * rs * sc[c + 2] + bi[c + 2]);
  o4.w = f2bf((v.w - mean) * rs * sc[c + 3] + bi[c + 3]);
  ((ushort4*)(out + (long)r * E))[threadIdx.x] = o4;
}

// ---------------- transpose f32[R,C] -> bf16[C,R] ----------------
__global__ __launch_bounds__(256)
void wtrans(const float* __restrict__ src, u16* __restrict__ dst, int R, int C) {
  __shared__ float t[32][33];
  const int c0 = blockIdx.x * 32, r0 = blockIdx.y * 32;
  const int tx = threadIdx.x & 31, ty = threadIdx.x >> 5;
#pragma unroll
  for (int i = 0; i < 32; i += 8) t[ty + i][tx] = src[(long)(r0 + ty + i) * C + c0 + tx];
  __syncthreads();
#pragma unroll
  for (int i = 0; i < 32; i += 8) dst[(long)(c0 + ty + i) * R + r0 + tx] = f2bf(t[tx][ty + i]);
}

// ---------------- merged per-layer weight transpose (4 weights, 1 launch) ----
struct WT4 {
  const float* s[4]; u16* d[4];
  int R[4], C[4], tx[4], st[4];
};
__global__ __launch_bounds__(256)
void wtrans4(WT4 a) {
  const int bid = blockIdx.x;
  const int wsel = (bid >= a.st[1]) + (bid >= a.st[2]) + (bid >= a.st[3]);
  const int t = bid - a.st[wsel];
  const int c0 = (t % a.tx[wsel]) * 32, r0 = (t / a.tx[wsel]) * 32;
  const float* src = a.s[wsel]; u16* dst = a.d[wsel];
  const int R = a.R[wsel], C = a.C[wsel];
  __shared__ float tt[32][33];
  const int tx = threadIdx.x & 31, ty = threadIdx.x >> 5;
#pragma unroll
  for (int i = 0; i < 32; i += 8) tt[ty + i][tx] = src[(long)(r0 + ty + i) * C + c0 + tx];
  __syncthreads();
#pragma unroll
  for (int i = 0; i < 32; i += 8) dst[(long)(c0 + ty + i) * R + r0 + tx] = f2bf(tt[tx][ty + i]);
}

// ---------------- small utility kernels ----------------
__global__ void cvt_bf(const float* __restrict__ in, u16* __restrict__ out, long n) {
  const long i = ((long)blockIdx.x * blockDim.x + threadIdx.x) * 4;
  if (i >= n) return;
  const float4 v = *(const float4*)(in + i);
  ushort4 o; o.x = f2bf(v.x); o.y = f2bf(v.y); o.z = f2bf(v.z); o.w = f2bf(v.w);
  *(ushort4*)(out + i) = o;
}

__global__ void zero_k(float4* p, long n) {
  long i = (long)blockIdx.x * blockDim.x + threadIdx.x;
  const long st = (long)gridDim.x * blockDim.x;
  const float4 z = make_float4(0.f, 0.f, 0.f, 0.f);
  for (; i < n; i += st) p[i] = z;
}

__global__ void reg_copy(const float* __restrict__ regs, float* __restrict__ x) {
  const int b = blockIdx.x >> 4, r = blockIdx.x & 15;
  const float4* sp = (const float4*)(regs + (long)r * E);
  float4* dp = (float4*)(x + ((long)(b * S + Tt + r)) * E);
  dp[threadIdx.x] = sp[threadIdx.x];
}

// ---------------- workspace layout (bytes, all 16-aligned) ----------------
constexpr long OFF_WQKV = 0L;                                // per-layer, reused
constexpr long OFF_WO   = OFF_WQKV + 3072L * 1024 * 2;
constexpr long OFF_WFC1 = OFF_WO   + 1024L * 1024 * 2;
constexpr long OFF_WFC2 = OFF_WFC1 + 4096L * 1024 * 2;
constexpr long OFF_WEMB = OFF_WFC2 + 1024L * 4096 * 2;
constexpr long OFF_WHEAD= OFF_WEMB + 1024L * 64 * 2;
constexpr long OFF_SMP  = OFF_WHEAD+ 256L * 1024 * 2;
constexpr long OFF_X    = OFF_SMP  + (long)ME * 64 * 2;
constexpr long OFF_H    = OFF_X    + (long)MR * E * 4;
constexpr long OFF_Q    = OFF_H    + (long)MR * E * 2;
constexpr long OFF_K    = OFF_Q    + 256L * SPAD * HD * 2;   // also split partial0
constexpr long OFF_VT   = OFF_K    + 256L * SPAD * HD * 2;   // also split partial1
constexpr long OFF_O    = OFF_VT   + 256L * SPAD * HD * 2;   // a1 overlays o
constexpr long OFF_HF   = OFF_O    + (long)MR * FF * 2;
constexpr long WS_NEED  = OFF_HF   + 256L * 1024 * 2;        // ~196 MB

extern "C" void kernel_launch(void* const* d_in, const int* in_sizes, int n_in,
                              void* d_out, int out_size, void* d_ws, size_t ws_size,
                              hipStream_t stream) {
  if (ws_size < (size_t)WS_NEED) return;

  const float* sample = (const float*)d_in[0];
  const float* W_emb  = (const float*)d_in[1];
  const float* b_emb  = (const float*)d_in[2];
  const float* pos    = (const float*)d_in[3];
  const float* regs   = (const float*)d_in[4];
  const float* ln1_s  = (const float*)d_in[5];
  const float* ln1_b  = (const float*)d_in[6];
  const float* W_qkv  = (const float*)d_in[7];
  const float* b_qkv  = (const float*)d_in[8];
  const float* W_o    = (const float*)d_in[9];
  const float* b_o    = (const float*)d_in[10];
  const float* ln2_s  = (const float*)d_in[11];
  const float* ln2_b  = (const float*)d_in[12];
  const float* W_fc1  = (const float*)d_in[13];
  const float* b_fc1  = (const float*)d_in[14];
  const float* W_fc2  = (const float*)d_in[15];
  const float* b_fc2  = (const float*)d_in[16];
  const float* lnf_s  = (const float*)d_in[17];
  const float* lnf_b  = (const float*)d_in[18];
  const float* W_head = (const float*)d_in[19];
  const float* b_head = (const float*)d_in[20];

  char* w = (char*)d_ws;
  u16* wqkvT = (u16*)(w + OFF_WQKV);
  u16* woT   = (u16*)(w + OFF_WO);
  u16* wfc1T = (u16*)(w + OFF_WFC1);
  u16* wfc2T = (u16*)(w + OFF_WFC2);
  u16* wembT = (u16*)(w + OFF_WEMB);
  u16* wheadT= (u16*)(w + OFF_WHEAD);
  u16* smp   = (u16*)(w + OFF_SMP);
  float* x   = (float*)(w + OFF_X);
  u16* h     = (u16*)(w + OFF_H);
  u16* qp    = (u16*)(w + OFF_Q);
  u16* kp    = (u16*)(w + OFF_K);
  u16* vtp   = (u16*)(w + OFF_VT);
  u16* o     = (u16*)(w + OFF_O);
  u16* a1    = (u16*)(w + OFF_O);   // overlay: o dead when a1 live
  u16* hf    = (u16*)(w + OFF_HF);

  // ---- one-time prep ----
  wtrans<<<dim3(32, 2, 1), 256, 0, stream>>>(W_emb,  wembT, 64, 1024);
  wtrans<<<dim3(8, 32, 1), 256, 0, stream>>>(W_head, wheadT, 1024, 256);
  cvt_bf<<<dim3(512), 256, 0, stream>>>(sample, smp, (long)ME * 64);
  zero_k<<<dim3(2048), 256, 0, stream>>>((float4*)qp, (3L * 256 * SPAD * HD * 2) / 16);

  // ---- embed + registers ----
  {
    GA g{}; g.A = smp; g.Bt = wembT; g.K = 64; g.Kc = 64; g.lda = 64; g.ldb = 64;
    g.Nrows = E; g.bias = b_emb; g.pos = pos; g.fout = x;
    gemm_bt<M_EMBED, 64><<<dim3(16, 64, 1), 256, 0, stream>>>(g);
  }
  reg_copy<<<dim3(256), 256, 0, stream>>>(regs, x);

  for (int L = 0; L < DEPTH; ++L) {
    // merged per-layer weight transpose (1 launch for qkv/o/fc1/fc2)
    {
      WT4 a;
      a.s[0] = W_qkv + (long)L * 1024 * 3072; a.d[0] = wqkvT; a.R[0] = 1024; a.C[0] = 3072; a.tx[0] = 96;  a.st[0] = 0;
      a.s[1] = W_o   + (long)L * 1024 * 1024; a.d[1] = woT;   a.R[1] = 1024; a.C[1] = 1024; a.tx[1] = 32;  a.st[1] = 3072;
      a.s[2] = W_fc1 + (long)L * 1024 * 4096; a.d[2] = wfc1T; a.R[2] = 1024; a.C[2] = 4096; a.tx[2] = 128; a.st[2] = 4096;
      a.s[3] = W_fc2 + (long)L * 4096 * 1024; a.d[3] = wfc2T; a.R[3] = 4096; a.C[3] = 1024; a.tx[3] = 32;  a.st[3] = 8192;
      wtrans4<<<dim3(12288), 256, 0, stream>>>(a);
    }

    // ln1: layer 0 standalone; layers 1..7 fused into red_ln of L-1
    if (L == 0)
      ln_k<<<dim3(MR), 256, 0, stream>>>(x, ln1_s, ln1_b, h, 0);
    {
      GA g{}; g.A = h; g.Bt = wqkvT;
      g.K = 1024; g.Kc = 1024; g.lda = 1024; g.ldb = 1024; g.Nrows = 3072;
      g.bias = b_qkv + L * 3072; g.qp = qp; g.kp = kp; g.vtp = vtp;
      gemm_bt<M_QKV, 128><<<dim3(24, 66, 1), 256, 0, stream>>>(g);
    }
    flash_k<<<dim3(5, 256, 1), 256, 0, stream>>>(qp, kp, vtp, o);
    {
      // oproj split-K x2: partials into kp/vtp (dead after flash consumed them)
      GA g{}; g.A = o; g.Bt = woT;
      g.K = 1024; g.Kc = 512; g.lda = 1024; g.ldb = 1024; g.Nrows = 1024; g.ldc = 1024;
      g.qp = kp; g.kp = vtp;
      gemm_bt<M_OPROJ, 128><<<dim3(8, 66, 2), 256, 0, stream>>>(g);
    }
    // reduce + b_o + residual, fused ln2 -> h
    red_ln<1><<<dim3(MR), 256, 0, stream>>>(x, kp, vtp, b_o + L * E,
                                            ln2_s + L * E, ln2_b + L * E, h);
    {
      GA g{}; g.A = h; g.Bt = wfc1T;
      g.K = 1024; g.Kc = 1024; g.lda = 1024; g.ldb = 1024; g.Nrows = 4096; g.ldc = 4096;
      g.bias = b_fc1 + L * FF; g.bout = a1;
      gemm_bt<M_FC1, 128><<<dim3(32, 66, 1), 256, 0, stream>>>(g);
    }
    {
      // fc2 split-K x2: kp/vtp dead again after oproj's red_ln
      GA g{}; g.A = a1; g.Bt = wfc2T;
      g.K = 4096; g.Kc = 2048; g.lda = 4096; g.ldb = 4096; g.Nrows = 1024; g.ldc = 1024;
      g.qp = kp; g.kp = vtp;
      gemm_bt<M_FC2, 128><<<dim3(8, 66, 2), 256, 0, stream>>>(g);
    }
    // reduce + b_fc2 + residual; fuse next layer's ln1 when L<7
    if (L < DEPTH - 1)
      red_ln<1><<<dim3(MR), 256, 0, stream>>>(x, kp, vtp, b_fc2 + L * E,
                                              ln1_s + (L + 1) * E, ln1_b + (L + 1) * E, h);
    else
      red_ln<0><<<dim3(MR), 256, 0, stream>>>(x, kp, vtp, b_fc2 + L * E,
                                              lnf_s, lnf_b, h);
  }

  ln_k<<<dim3(256), 256, 0, stream>>>(x, lnf_s, lnf_b, hf, 1);
  {
    GA g{}; g.A = hf; g.Bt = wheadT; g.K = 1024; g.Kc = 1024; g.lda = 1024; g.ldb = 1024;
    g.Nrows = LAT; g.ldc = LAT; g.bias = b_head; g.fout = (float*)d_out;
    gemm_bt<M_HEAD, 64><<<dim3(4, 2, 1), 256, 0, stream>>>(g);
  }
}